// Round 7
// baseline (358.377 us; speedup 1.0000x reference)
//
#include <hip/hip_runtime.h>
#include <hip/hip_bf16.h>
#include <math.h>

#define B_  2
#define T_  1024
#define D_  2048
#define H_  16
#define DH_ 128
#define M_  2048          // B_*T_
#define DR_ 1024          // D_/2
#define CH_  16           // EMA chunk length
#define NCH_ 64           // chunks per sequence (T_/CH_)

typedef __attribute__((ext_vector_type(8))) short short8;
typedef __attribute__((ext_vector_type(4))) short sh4;
typedef __attribute__((ext_vector_type(4))) float f32x4;

// async global->LDS, 16B per lane, dest = wave-uniform base + lane*16
__device__ __forceinline__ void gld16(const __hip_bfloat16* g, __hip_bfloat16* l) {
  __builtin_amdgcn_global_load_lds(
      (const __attribute__((address_space(1))) unsigned int*)g,
      (__attribute__((address_space(3))) unsigned int*)l, 16, 0, 0);
}

// ---------------------------------------------------------------------------
// bf16 MFMA GEMM: C = act(A * B^T + bias). A:[M,K] bf16 rm, B:[N,K] bf16 rm.
// BM x 128 tile, BK=32, double-buffered LDS, 2-phase pipeline:
// stage(t+1) issued BEFORE compute(t); ONE __syncthreads per K-step.
// LDS = 32KB (BM=128) / 24KB (BM=64) -> 4-5 blocks/CU: the barrier's
// vmcnt(0) drain is covered by other resident blocks' waves (m114 TLP),
// which is how the m97-structure reaches ~900 TF at this tile size.
// 256 threads = 4 waves in 2x2.
// CMODE 0: C fp32 [M,N].   CMODE 1: Cb bf16 [M,N] only.
// CMODE 4: merged KV. col<2048: C fp32 heads + Cb bf16 heads (k).
//          col>=2048: C2 fp32 heads + Cb2 bf16 transposed [b,h,dh,t] (v).
// ---------------------------------------------------------------------------
template<int BM, int CMODE, bool SILU>
__global__ __launch_bounds__(256)
void gemm_mfma(const __hip_bfloat16* __restrict__ A,
               const __hip_bfloat16* __restrict__ Bm,
               const float* __restrict__ bias,
               float* __restrict__ C, __hip_bfloat16* __restrict__ Cb,
               float* __restrict__ C2, __hip_bfloat16* __restrict__ Cb2,
               int M, int N, int K)
{
  constexpr int NI = BM / 32;           // A-fragment rows per wave (4 or 2)
  constexpr int AC = BM / 64;           // A gld16 calls per wave per stage
  __shared__ __hip_bfloat16 As[2][BM * 32];
  __shared__ __hip_bfloat16 Bs[2][128 * 32];
  const int tid  = threadIdx.x;
  const int wave = tid >> 6;
  const int lane = tid & 63;
  const int m0 = blockIdx.y * BM;
  const int n0 = blockIdx.x * 128;
  const int wm = (wave >> 1) * (BM / 2);   // wave's row half
  const int wn = (wave & 1) * 64;          // wave's col half

  const int srow = lane >> 2;              // 0..15 row within 16-row group
  const int scol = (lane & 3) * 8;         // bf16 element offset in k
  const __hip_bfloat16* Ag = A  + (size_t)(m0 + wave * (BM / 4) + srow) * K + scol;
  const __hip_bfloat16* Bg = Bm + (size_t)(n0 + wave * 32 + srow) * K + scol;

  const int fr = lane & 15;                // fragment row (m/n index)
  const int fk = (lane >> 4) * 8;          // fragment k offset

  f32x4 acc[NI][4];
  #pragma unroll
  for (int i = 0; i < NI; ++i)
    #pragma unroll
    for (int j = 0; j < 4; ++j) acc[i][j] = (f32x4)0.f;

  // stage one BK=32 tile into buffer bf
  auto stage = [&](int bf, int k0) {
    #pragma unroll
    for (int c = 0; c < AC; ++c)
      gld16(Ag + k0 + (size_t)(c * 16) * K,
            &As[bf][(wave * (BM / 4) + c * 16) * 32]);
    #pragma unroll
    for (int c = 0; c < 2; ++c)
      gld16(Bg + k0 + (size_t)(c * 16) * K,
            &Bs[bf][(wave * 32 + c * 16) * 32]);
  };

  const int NT = K >> 5;
  stage(0, 0);
  __syncthreads();                         // prologue drain (vmcnt(0))
  int cur = 0;
  for (int t = 0; t < NT; ++t) {
    if (t + 1 < NT) stage(cur ^ 1, (t + 1) * 32);   // issue next tile FIRST
    short8 af[NI], bfr[4];
    #pragma unroll
    for (int i = 0; i < NI; ++i)
      af[i]  = *(const short8*)&As[cur][(wm + i * 16 + fr) * 32 + fk];
    #pragma unroll
    for (int j = 0; j < 4; ++j)
      bfr[j] = *(const short8*)&Bs[cur][(wn + j * 16 + fr) * 32 + fk];
    #pragma unroll
    for (int i = 0; i < NI; ++i)
      #pragma unroll
      for (int j = 0; j < 4; ++j)
        acc[i][j] = __builtin_amdgcn_mfma_f32_16x16x32_bf16(af[i], bfr[j], acc[i][j], 0, 0, 0);
    __syncthreads();   // vmcnt(0)+lgkmcnt(0): next tile landed, reads done
    cur ^= 1;
  }

  // C/D layout (m89-verified): col = lane&15, row = (lane>>4)*4 + reg
  #pragma unroll
  for (int i = 0; i < NI; ++i) {
    #pragma unroll
    for (int j = 0; j < 4; ++j) {
      const int row0 = m0 + wm + i * 16 + (lane >> 4) * 4;
      const int col  = n0 + wn + j * 16 + (lane & 15);
      float vr[4];
      #pragma unroll
      for (int r = 0; r < 4; ++r) {
        float v = acc[i][j][r];
        if (bias) v += bias[col];
        if (SILU) v = v / (1.f + __expf(-v));
        vr[r] = v;
      }
      if (CMODE == 0) {
        #pragma unroll
        for (int r = 0; r < 4; ++r) C[(size_t)(row0 + r) * N + col] = vr[r];
      } else if (CMODE == 1) {
        #pragma unroll
        for (int r = 0; r < 4; ++r) Cb[(size_t)(row0 + r) * N + col] = __float2bfloat16(vr[r]);
      } else {  // CMODE 4
        const int bb = row0 >> 10, t0v = row0 & 1023;   // row = b*T + t
        if (col < D_) {                                  // K head
          const int hh = col >> 7, dd = col & 127;
          #pragma unroll
          for (int r = 0; r < 4; ++r) {
            const size_t idx = (((size_t)(bb * H_ + hh)) * T_ + t0v + r) * DH_ + dd;
            C[idx] = vr[r];
            Cb[idx] = __float2bfloat16(vr[r]);
          }
        } else {                                         // V head (+ transposed bf16)
          const int c2 = col - D_;
          const int hh = c2 >> 7, dd = c2 & 127;
          #pragma unroll
          for (int r = 0; r < 4; ++r)
            C2[(((size_t)(bb * H_ + hh)) * T_ + t0v + r) * DH_ + dd] = vr[r];
          __hip_bfloat16 tmp[4];
          #pragma unroll
          for (int r = 0; r < 4; ++r) tmp[r] = __float2bfloat16(vr[r]);
          *(sh4*)(Cb2 + (((size_t)(bb * H_ + hh)) * DH_ + dd) * T_ + t0v) = *(const sh4*)tmp;
        }
      }
    }
  }
}

// ---------------------------------------------------------------------------
// prep_all: one launch for x-prep + 5 weight conversions.
// y==0 (x-blocks 0..255): read x once (float4), write xb (bf16, 8B store),
//   local EMA scan per 16-row chunk (fp32), and compact chunk-final lf.
// y==1..5: fp32->bf16 weight conversion (16B short8 stores).
// ---------------------------------------------------------------------------
__global__ __launch_bounds__(256)
void prep_all(const float* __restrict__ x, __hip_bfloat16* __restrict__ xb,
              float* __restrict__ l2, float* __restrict__ lf,
              const float* __restrict__ s1, const float* __restrict__ s2,
              const float* __restrict__ s3, const float* __restrict__ s4,
              const float* __restrict__ s5,
              __hip_bfloat16* d1, __hip_bfloat16* d2, __hip_bfloat16* d3,
              __hip_bfloat16* d4, __hip_bfloat16* d5,
              int n1, int n2, int n3, int n4, int n5)
{
  if (blockIdx.y == 0) {
    const int bid = blockIdx.x;
    if (bid >= 256) return;
    const int dblk = bid & 1;
    const int ch   = (bid >> 1) & 63;
    const int b    = bid >> 7;
    const int t0 = ch * CH_;
    const int d  = dblk * 1024 + threadIdx.x * 4;
    const float* xp = x  + (size_t)b * T_ * D_ + d;
    float*       lp = l2 + (size_t)b * T_ * D_ + d;
    __hip_bfloat16* xo = xb + (size_t)b * T_ * D_ + d;
    float4 s = make_float4(0.f, 0.f, 0.f, 0.f);
    #pragma unroll 4
    for (int t = t0; t < t0 + CH_; ++t) {
      float4 v = *(const float4*)(xp + (size_t)t * D_);
      __hip_bfloat16 tmp[4] = {__float2bfloat16(v.x), __float2bfloat16(v.y),
                               __float2bfloat16(v.z), __float2bfloat16(v.w)};
      *(sh4*)(xo + (size_t)t * D_) = *(const sh4*)tmp;
      s.x = 0.9f * s.x + 0.1f * v.x;
      s.y = 0.9f * s.y + 0.1f * v.y;
      s.z = 0.9f * s.z + 0.1f * v.z;
      s.w = 0.9f * s.w + 0.1f * v.w;
      *(float4*)(lp + (size_t)t * D_) = s;
    }
    // compact chunk-final for the carry computation in fuse_router
    *(float4*)(lf + ((size_t)b * NCH_ + ch) * D_ + d) = s;
    return;
  }
  const float* s; __hip_bfloat16* d; int n;
  switch (blockIdx.y) {
    case 1: s = s1; d = d1; n = n1; break;
    case 2: s = s2; d = d2; n = n2; break;
    case 3: s = s3; d = d3; n = n3; break;
    case 4: s = s4; d = d4; n = n4; break;
    default: s = s5; d = d5; n = n5; break;
  }
  const int i = (blockIdx.x * 256 + threadIdx.x) * 8;
  if (i < n) {
    float4 a = *(const float4*)(s + i);
    float4 b = *(const float4*)(s + i + 4);
    __hip_bfloat16 t[8] = {__float2bfloat16(a.x), __float2bfloat16(a.y),
                           __float2bfloat16(a.z), __float2bfloat16(a.w),
                           __float2bfloat16(b.x), __float2bfloat16(b.y),
                           __float2bfloat16(b.z), __float2bfloat16(b.w)};
    *(short8*)(d + i) = *(const short8*)t;
  }
}

// ---------------------------------------------------------------------------
// fuse_router: per block, 8 consecutive rows (all in ONE batch b and ONE
// EMA chunk ch since 8 | 16).
// Phase 1: lam = softmax(hdn @ rw2^T + rb2) per row (32-lane group dot).
// Phase 1b: carry(b,ch,:) computed inline as weighted sum over lf (L3-hot,
//   <=63 fma iterations/thread).
// Phase 2: fused = lam0*x + lam1*(l2 + 0.9^(off+1)*carry) + lam2*l3 -> bf16.
// ---------------------------------------------------------------------------
__global__ __launch_bounds__(256)
void fuse_router(const float* __restrict__ x, const float* __restrict__ l2,
                 const float* __restrict__ l3m, const float* __restrict__ hdn,
                 const float* __restrict__ rw2, const float* __restrict__ rb2,
                 const float* __restrict__ lf, float* __restrict__ lam,
                 __hip_bfloat16* __restrict__ fb)
{
  __shared__ float lamS[8][3];
  const int tid = threadIdx.x;
  const int g = tid >> 5, l32 = tid & 31;
  const int m = blockIdx.x * 8 + g;
  const float* hp = hdn + (size_t)m * DR_;
  float s0 = 0.f, s1 = 0.f, s2 = 0.f;
  #pragma unroll
  for (int it = 0; it < 8; ++it) {
    const int k = l32 * 4 + it * 128;
    float4 h4 = *(const float4*)(hp + k);
    float4 w0 = *(const float4*)(rw2 + k);
    float4 w1 = *(const float4*)(rw2 + DR_ + k);
    float4 w2 = *(const float4*)(rw2 + 2 * DR_ + k);
    s0 += h4.x * w0.x + h4.y * w0.y + h4.z * w0.z + h4.w * w0.w;
    s1 += h4.x * w1.x + h4.y * w1.y + h4.z * w1.z + h4.w * w1.w;
    s2 += h4.x * w2.x + h4.y * w2.y + h4.z * w2.z + h4.w * w2.w;
  }
  #pragma unroll
  for (int off = 16; off > 0; off >>= 1) {
    s0 += __shfl_xor(s0, off);
    s1 += __shfl_xor(s1, off);
    s2 += __shfl_xor(s2, off);
  }
  if (l32 == 0) {
    s0 += rb2[0]; s1 += rb2[1]; s2 += rb2[2];
    float mx = fmaxf(s0, fmaxf(s1, s2));
    float e0 = __expf(s0 - mx), e1 = __expf(s1 - mx), e2 = __expf(s2 - mx);
    float inv = 1.f / (e0 + e1 + e2);
    lam[(size_t)m * 3 + 0] = e0 * inv;
    lam[(size_t)m * 3 + 1] = e1 * inv;
    lam[(size_t)m * 3 + 2] = e2 * inv;
    lamS[g][0] = e0 * inv; lamS[g][1] = e1 * inv; lamS[g][2] = e2 * inv;
  }

  // inline carry for this block's single (b, ch):
  // carry = sum_{j<ch} (0.9^16)^(ch-1-j) * lf[b,j,:]
  const int m0b = blockIdx.x * 8;
  const int bb  = m0b >> 10;
  const int ch  = (m0b & 1023) >> 4;
  const int c   = tid * 8;
  float4 cv0 = make_float4(0.f, 0.f, 0.f, 0.f);
  float4 cv1 = make_float4(0.f, 0.f, 0.f, 0.f);
  {
    float w = 1.f;
    for (int j = ch - 1; j >= 0; --j) {
      const float* lp = lf + ((size_t)bb * NCH_ + j) * D_ + c;
      float4 a0 = *(const float4*)(lp);
      float4 a1 = *(const float4*)(lp + 4);
      cv0.x += w * a0.x; cv0.y += w * a0.y; cv0.z += w * a0.z; cv0.w += w * a0.w;
      cv1.x += w * a1.x; cv1.y += w * a1.y; cv1.z += w * a1.z; cv1.w += w * a1.w;
      w *= 0.18530201888518416f;              // 0.9^16
    }
  }
  __syncthreads();

  const int base = m0b & 15;                  // off base (0 or 8)
  #pragma unroll
  for (int r = 0; r < 8; ++r) {
    const int mm = m0b + r;
    const float pw = __expf((float)(base + r + 1) * -0.105360515657f);  // 0.9^(off+1)
    const float u0 = lamS[r][0], u1 = lamS[r][1], u2 = lamS[r][2];
    const float* xp = x   + (size_t)mm * D_ + c;
    const float* ep = l2  + (size_t)mm * D_ + c;
    const float* gp = l3m + (size_t)bb * D_ + c;
    __hip_bfloat16 tmp[8];
    {
      float4 xv = *(const float4*)(xp);
      float4 ev = *(const float4*)(ep);
      float4 gv = *(const float4*)(gp);
      tmp[0] = __float2bfloat16(u0 * xv.x + u1 * (ev.x + pw * cv0.x) + u2 * gv.x);
      tmp[1] = __float2bfloat16(u0 * xv.y + u1 * (ev.y + pw * cv0.y) + u2 * gv.y);
      tmp[2] = __float2bfloat16(u0 * xv.z + u1 * (ev.z + pw * cv0.z) + u2 * gv.z);
      tmp[3] = __float2bfloat16(u0 * xv.w + u1 * (ev.w + pw * cv0.w) + u2 * gv.w);
    }
    {
      float4 xv = *(const float4*)(xp + 4);
      float4 ev = *(const float4*)(ep + 4);
      float4 gv = *(const float4*)(gp + 4);
      tmp[4] = __float2bfloat16(u0 * xv.x + u1 * (ev.x + pw * cv1.x) + u2 * gv.x);
      tmp[5] = __float2bfloat16(u0 * xv.y + u1 * (ev.y + pw * cv1.y) + u2 * gv.y);
      tmp[6] = __float2bfloat16(u0 * xv.z + u1 * (ev.z + pw * cv1.z) + u2 * gv.z);
      tmp[7] = __float2bfloat16(u0 * xv.w + u1 * (ev.w + pw * cv1.w) + u2 * gv.w);
    }
    *(short8*)(fb + (size_t)mm * D_ + c) = *(const short8*)tmp;
  }
}

// ---------------------------------------------------------------------------
// MFMA flash attention. 64-row Q-tile per block, 4 waves x 16 q-rows,
// 64-key K-tiles, 16x16x32 bf16 MFMA for QK^T and PV.
// DOUBLE-BUFFERED K/V LDS, ONE barrier per iteration.  Ps is wave-private.
// LDS = 80,896 B -> 2 blocks/CU.  Grid: 1-D 512 with anti-correlated qt
// remap (co-resident pairs sum to 17 tile-iters).  Q fragments global->reg.
// ---------------------------------------------------------------------------
__global__ __launch_bounds__(256)
void flash_mfma(const __hip_bfloat16* __restrict__ qg,
                const __hip_bfloat16* __restrict__ kg,
                const __hip_bfloat16* __restrict__ vg,
                __hip_bfloat16* __restrict__ og)
{
  __shared__ __hip_bfloat16 Ks[2][64 * 136];
  __shared__ __hip_bfloat16 Vt[2][128 * 72];
  __shared__ __hip_bfloat16 Ps[64 * 72];
  const int tid  = threadIdx.x;
  const int wave = tid >> 6, lane = tid & 63;
  const int L    = blockIdx.x;
  const int halfg = L >> 8, idx = L & 255;
  const int bh = (idx >> 4) | (halfg << 4);
  const int qt = halfg ? (15 - (idx & 15)) : (idx & 15);
  const int b = bh >> 4, h = bh & 15;
  const int q0 = qt * 64;
  const int lo = lane & 15, hi = lane >> 4;

  short8 aq[4];
  {
    const __hip_bfloat16* qsrc = qg + (size_t)(b * T_ + q0 + wave * 16 + lo) * D_ + h * DH_;
    #pragma unroll
    for (int kk = 0; kk < 4; ++kk)
      aq[kk] = *(const short8*)(qsrc + kk * 32 + hi * 8);
  }

  f32x4 oacc[8];
  #pragma unroll
  for (int i = 0; i < 8; ++i) oacc[i] = (f32x4)0.f;
  float mrow[4] = {-INFINITY, -INFINITY, -INFINITY, -INFINITY};
  float lrow[4] = {0.f, 0.f, 0.f, 0.f};

  const __hip_bfloat16* kbp = kg + (size_t)bh * T_ * DH_;
  const __hip_bfloat16* vbp = vg + (size_t)bh * DH_ * T_;
  const float scale = 0.08838834764831845f;      // 1/sqrt(128)

  short8 kreg[4], vreg[4];
  auto load_tile = [&](int k0) {
    #pragma unroll
    for (int i = 0; i < 4; ++i) {
      const int ci = tid + 256 * i;
      const int r = ci >> 4, j = ci & 15;
      kreg[i] = *(const short8*)(kbp + (size_t)(k0 + r) * DH_ + j * 8);
      const int dd = ci >> 3, j2 = ci & 7;
      vreg[i] = *(const short8*)(vbp + (size_t)dd * T_ + k0 + j2 * 8);
    }
  };
  auto write_lds = [&](int bf) {
    #pragma unroll
    for (int i = 0; i < 4; ++i) {
      const int ci = tid + 256 * i;
      const int r = ci >> 4, j = ci & 15;
      *(short8*)&Ks[bf][r * 136 + j * 8] = kreg[i];
      const int dd = ci >> 3, j2 = ci & 7;
      *(short8*)&Vt[bf][dd * 72 + j2 * 8] = vreg[i];
    }
  };

  load_tile(0);
  write_lds(0);                     // implicit vmcnt wait on tile-0 loads
  if (qt > 0) load_tile(64);        // tile 1 in flight across barrier
  __syncthreads();

  for (int kt = 0; kt <= qt; ++kt) {
    const int cur = kt & 1;
    f32x4 sc[4];
    __builtin_amdgcn_s_setprio(1);
    #pragma unroll
    for (int nt = 0; nt < 4; ++nt) {
      sc[nt] = (f32x4)0.f;
      #pragma unroll
      for (int kk = 0; kk < 4; ++kk) {
        short8 bk = *(const short8*)&Ks[cur][(nt * 16 + lo) * 136 + kk * 32 + hi * 8];
        sc[nt] = __builtin_amdgcn_mfma_f32_16x16x32_bf16(aq[kk], bk, sc[nt], 0, 0, 0);
      }
    }
    __builtin_amdgcn_s_setprio(0);
    #pragma unroll
    for (int nt = 0; nt < 4; ++nt)
      #pragma unroll
      for (int r = 0; r < 4; ++r) sc[nt][r] *= scale;
    if (kt == qt) {                           // mask only the diagonal tile
      const int qrow = q0 + wave * 16 + hi * 4;
      #pragma unroll
      for (int nt = 0; nt < 4; ++nt) {
        const int key = qt * 64 + nt * 16 + lo;
        #pragma unroll
        for (int r = 0; r < 4; ++r)
          if (key > qrow + r) sc[nt][r] = -1e30f;
      }
    }
    float alpha[4];
    #pragma unroll
    for (int r = 0; r < 4; ++r) {
      float mx = fmaxf(fmaxf(sc[0][r], sc[1][r]), fmaxf(sc[2][r], sc[3][r]));
      mx = fmaxf(mx, __shfl_xor(mx, 1));
      mx = fmaxf(mx, __shfl_xor(mx, 2));
      mx = fmaxf(mx, __shfl_xor(mx, 4));
      mx = fmaxf(mx, __shfl_xor(mx, 8));
      const float nm = fmaxf(mrow[r], mx);
      alpha[r] = __expf(mrow[r] - nm);
      mrow[r] = nm;
      float ls = 0.f;
      #pragma unroll
      for (int nt = 0; nt < 4; ++nt) {
        float p = __expf(sc[nt][r] - nm);
        sc[nt][r] = p;
        ls += p;
      }
      ls += __shfl_xor(ls, 1);
      ls += __shfl_xor(ls, 2);
      ls += __shfl_xor(ls, 4);
      ls += __shfl_xor(ls, 8);
      lrow[r] = lrow[r] * alpha[r] + ls;
    }
    #pragma unroll
    for (int nt = 0; nt < 4; ++nt)
      #pragma unroll
      for (int r = 0; r < 4; ++r)
        Ps[(wave * 16 + hi * 4 + r) * 72 + nt * 16 + lo] = __float2bfloat16(sc[nt][r]);
    #pragma unroll
    for (int n2 = 0; n2 < 8; ++n2)
      #pragma unroll
      for (int r = 0; r < 4; ++r) oacc[n2][r] *= alpha[r];
    short8 ap[2];
    #pragma unroll
    for (int k2 = 0; k2 < 2; ++k2)
      ap[k2] = *(const short8*)&Ps[(wave * 16 + lo) * 72 + k2 * 32 + hi * 8];
    __builtin_amdgcn_s_setprio(1);
    #pragma unroll
    for (int n2 = 0; n2 < 8; ++n2) {
      #pragma unroll
      for (int k2 = 0; k2 < 2; ++k2) {
        short8 bv = *(const short8*)&Vt[cur][(n2 * 16 + lo) * 72 + k2 * 32 + hi * 8];
        oacc[n2] = __builtin_amdgcn_mfma_f32_16x16x32_bf16(ap[k2], bv, oacc[n2], 0, 0, 0);
      }
    }
    __builtin_amdgcn_s_setprio(0);
    if (kt < qt) {
      write_lds(cur ^ 1);           // vmcnt waits only on tile kt+1 loads
      if (kt + 1 < qt) load_tile((kt + 2) * 64);
    }
    __syncthreads();                // single barrier per iteration
  }

  float inv[4];
  #pragma unroll
  for (int r = 0; r < 4; ++r) inv[r] = 1.f / lrow[r];
  __hip_bfloat16* od = og + (size_t)(b * T_ + q0 + wave * 16 + hi * 4) * D_ + h * DH_;
  #pragma unroll
  for (int n2 = 0; n2 < 8; ++n2)
    #pragma unroll
    for (int r = 0; r < 4; ++r)
      od[(size_t)r * D_ + n2 * 16 + lo] = __float2bfloat16(oacc[n2][r] * inv[r]);
}

// ---------------------------------------------------------------------------
extern "C" void kernel_launch(void* const* d_in, const int* in_sizes, int n_in,
                              void* d_out, int out_size, void* d_ws, size_t ws_size,
                              hipStream_t stream)
{
  const float* x   = (const float*)d_in[0];
  const float* l3m = (const float*)d_in[1];
  const float* wq  = (const float*)d_in[2];
  const float* wk  = (const float*)d_in[3];
  const float* wv  = (const float*)d_in[4];
  const float* wo  = (const float*)d_in[5];
  const float* rw1 = (const float*)d_in[6];
  const float* rb1 = (const float*)d_in[7];
  const float* rw2 = (const float*)d_in[8];
  const float* rb2 = (const float*)d_in[9];

  float* out = (float*)d_out;                 // [b,t,d]      4,194,304 f32
  float* kh  = out + 4194304;                 // [b,h,t,dh]   4,194,304 f32
  float* vh  = out + 8388608;                 // [b,h,t,dh]   4,194,304 f32
  float* lam = out + 12582912;                // [b,t,3]          6,144 f32

  // ws layout (80 MB):
  char* wsb = (char*)d_ws;
  float*          l2_f32 = (float*)(wsb);                        // 16 MB (local scan)
  float*          hdn    = (float*)(wsb + (16u << 20));          //  8 MB
  __hip_bfloat16* wkb    = (__hip_bfloat16*)(wsb + (24u << 20)); //  8 MB \ contiguous
  __hip_bfloat16* wvb    = (__hip_bfloat16*)(wsb + (32u << 20)); //  8 MB / [4096,2048]
  __hip_bfloat16* wob    = (__hip_bfloat16*)(wsb + (40u << 20)); //  8 MB
  __hip_bfloat16* fusedb = (__hip_bfloat16*)(wsb + (48u << 20)); //  8 MB
  __hip_bfloat16* attnb  = (__hip_bfloat16*)(wsb + (56u << 20)); //  8 MB (written step 6)
  __hip_bfloat16* khb    = (__hip_bfloat16*)(wsb + (64u << 20)); //  8 MB bf16 heads
  __hip_bfloat16* vtb    = (__hip_bfloat16*)(wsb + (72u << 20)); //  8 MB bf16 [b,h,dh,t]
  float*          lf     = (float*)(wsb + (57u << 20));   // 1 MB chunk-finals (in attnb region; dead before flash)
  // d_out scratch reuse (regions written later in the stream order):
  __hip_bfloat16* wqb  = (__hip_bfloat16*)kh;                    // [16,24 MB) of d_out
  __hip_bfloat16* rw1b = (__hip_bfloat16*)kh + 4194304;          // [24,28 MB)
  __hip_bfloat16* xb   = (__hip_bfloat16*)vh;                    // [32,40 MB)
  __hip_bfloat16* qb   = (__hip_bfloat16*)out;                   // [0,8 MB); out written last

  dim3 blk(256);

  // 1. prep (x -> xb + EMA local scan + lf) and weight cvts, one launch
  prep_all<<<dim3(2048, 6), blk, 0, stream>>>(x, xb, l2_f32, lf,
                                              wq, wk, wv, wo, rw1,
                                              wqb, wkb, wvb, wob, rw1b,
                                              D_ * D_, D_ * D_, D_ * D_, D_ * D_, DR_ * D_);
  // 2. qb = bf16(x @ wq^T)   (64x128 tiles -> 512 WGs)
  gemm_mfma<64, 1, false><<<dim3(16, 32), blk, 0, stream>>>(xb, wqb, nullptr, nullptr, qb, nullptr, nullptr, M_, D_, D_);
  // 3. hdn = silu(q @ rw1^T + rb1)   (64x128 -> 256 WGs)
  gemm_mfma<64, 0, true><<<dim3(8, 32), blk, 0, stream>>>(qb, rw1b, rb1, hdn, nullptr, nullptr, nullptr, M_, DR_, D_);
  // 4. router + inline EMA carry + fuse in one kernel (writes lam, fusedb)
  fuse_router<<<dim3(256), blk, 0, stream>>>(x, l2_f32, l3m, hdn, rw2, rb2, lf, lam, fusedb);
  // 5. merged KV GEMM (N=4096): kh fp32+khb bf16 heads; vh fp32+vtb bf16 transposed
  gemm_mfma<128, 4, false><<<dim3(32, 16), blk, 0, stream>>>(fusedb, wkb, nullptr, kh, khb, vh, vtb, M_, 2 * D_, D_);
  // 6. MFMA flash attention -> bf16 attnb [b,t,d]  (balanced 1-D grid)
  flash_mfma<<<dim3(512), blk, 0, stream>>>(qb, khb, vtb, attnb);
  // 7. out = attn @ wo^T   (64x128 -> 512 WGs)
  gemm_mfma<64, 0, false><<<dim3(16, 32), blk, 0, stream>>>(attnb, wob, nullptr, out, nullptr, nullptr, nullptr, M_, D_, D_);
}

// Round 8
// 341.170 us; speedup vs baseline: 1.0504x; 1.0504x over previous
//
#include <hip/hip_runtime.h>
#include <hip/hip_bf16.h>
#include <math.h>

#define B_  2
#define T_  1024
#define D_  2048
#define H_  16
#define DH_ 128
#define M_  2048          // B_*T_
#define DR_ 1024          // D_/2
#define CH_  16           // EMA chunk length
#define NCH_ 64           // chunks per sequence (T_/CH_)

typedef __attribute__((ext_vector_type(8))) short short8;
typedef __attribute__((ext_vector_type(4))) short sh4;
typedef __attribute__((ext_vector_type(4))) float f32x4;

// async global->LDS, 16B per lane, dest = wave-uniform base + lane*16
__device__ __forceinline__ void gld16(const __hip_bfloat16* g, __hip_bfloat16* l) {
  __builtin_amdgcn_global_load_lds(
      (const __attribute__((address_space(1))) unsigned int*)g,
      (__attribute__((address_space(3))) unsigned int*)l, 16, 0, 0);
}

// ---------------------------------------------------------------------------
// bf16 MFMA GEMM: C = act(A * B^T + bias). A:[M,K] bf16 rm, B:[N,K] bf16 rm.
// BM x 128 tile, BK=64 (two 32-col halves), double-buffered LDS, 2-phase
// pipeline: stage(t+1) issued BEFORE compute(t); one __syncthreads per
// K-step.  256 threads = 4 waves in 2x2.
// KNOWN-GOOD plateau config (~51us KV): BK=32 (r7), counted-vmcnt 4-buf
// (r3), and XCD swizzle (r6) all regressed — do not touch without the
// full 8-wave 256-square template (which can't win at M=2048: <=128 WGs).
// CMODE 0: C fp32 [M,N].   CMODE 1: Cb bf16 [M,N] only.
// CMODE 4: merged KV. col<2048: C fp32 heads + Cb bf16 heads (k).
//          col>=2048: C2 fp32 heads + Cb2 bf16 transposed [b,h,dh,t] (v).
// ---------------------------------------------------------------------------
template<int BM, int CMODE, bool SILU>
__global__ __launch_bounds__(256)
void gemm_mfma(const __hip_bfloat16* __restrict__ A,
               const __hip_bfloat16* __restrict__ Bm,
               const float* __restrict__ bias,
               float* __restrict__ C, __hip_bfloat16* __restrict__ Cb,
               float* __restrict__ C2, __hip_bfloat16* __restrict__ Cb2,
               int M, int N, int K)
{
  constexpr int NI = BM / 32;           // A-fragment rows per wave (4 or 2)
  constexpr int AC = BM / 64;           // A gld16 calls per wave per half (2 or 1)
  __shared__ __hip_bfloat16 As[2][2][BM * 32];    // [buf][k-half][BM x 32]
  __shared__ __hip_bfloat16 Bs[2][2][128 * 32];
  const int tid  = threadIdx.x;
  const int wave = tid >> 6;
  const int lane = tid & 63;
  const int m0 = blockIdx.y * BM;
  const int n0 = blockIdx.x * 128;
  const int wm = (wave >> 1) * (BM / 2);   // wave's row half
  const int wn = (wave & 1) * 64;          // wave's col half

  const int srow = lane >> 2;              // 0..15 row within 16-row group
  const int scol = (lane & 3) * 8;         // bf16 element offset in k
  const __hip_bfloat16* Ag = A  + (size_t)(m0 + wave * (BM / 4) + srow) * K + scol;
  const __hip_bfloat16* Bg = Bm + (size_t)(n0 + wave * 32 + srow) * K + scol;

  const int fr = lane & 15;                // fragment row (m/n index)
  const int fk = (lane >> 4) * 8;          // fragment k offset

  f32x4 acc[NI][4];
  #pragma unroll
  for (int i = 0; i < NI; ++i)
    #pragma unroll
    for (int j = 0; j < 4; ++j) acc[i][j] = (f32x4)0.f;

  // stage one BK=64 tile (both 32-col halves) into buffer bf
  auto stage = [&](int bf, int k0) {
    #pragma unroll
    for (int h = 0; h < 2; ++h) {
      #pragma unroll
      for (int c = 0; c < AC; ++c)
        gld16(Ag + k0 + h * 32 + (size_t)(c * 16) * K,
              &As[bf][h][(wave * (BM / 4) + c * 16) * 32]);
      #pragma unroll
      for (int c = 0; c < 2; ++c)
        gld16(Bg + k0 + h * 32 + (size_t)(c * 16) * K,
              &Bs[bf][h][(wave * 32 + c * 16) * 32]);
    }
  };

  stage(0, 0);
  __syncthreads();                         // prologue drain (vmcnt(0))
  int cur = 0;
  for (int k0 = 0; k0 < K; k0 += 64) {
    if (k0 + 64 < K) stage(cur ^ 1, k0 + 64);   // issue next tile FIRST
    #pragma unroll
    for (int h = 0; h < 2; ++h) {
      short8 af[NI], bfr[4];
      #pragma unroll
      for (int i = 0; i < NI; ++i)
        af[i]  = *(const short8*)&As[cur][h][(wm + i * 16 + fr) * 32 + fk];
      #pragma unroll
      for (int j = 0; j < 4; ++j)
        bfr[j] = *(const short8*)&Bs[cur][h][(wn + j * 16 + fr) * 32 + fk];
      #pragma unroll
      for (int i = 0; i < NI; ++i)
        #pragma unroll
        for (int j = 0; j < 4; ++j)
          acc[i][j] = __builtin_amdgcn_mfma_f32_16x16x32_bf16(af[i], bfr[j], acc[i][j], 0, 0, 0);
    }
    __syncthreads();   // vmcnt(0)+lgkmcnt(0) drain: next tile landed, reads done
    cur ^= 1;
  }

  // C/D layout (m89-verified): col = lane&15, row = (lane>>4)*4 + reg
  #pragma unroll
  for (int i = 0; i < NI; ++i) {
    #pragma unroll
    for (int j = 0; j < 4; ++j) {
      const int row0 = m0 + wm + i * 16 + (lane >> 4) * 4;
      const int col  = n0 + wn + j * 16 + (lane & 15);
      float vr[4];
      #pragma unroll
      for (int r = 0; r < 4; ++r) {
        float v = acc[i][j][r];
        if (bias) v += bias[col];
        if (SILU) v = v / (1.f + __expf(-v));
        vr[r] = v;
      }
      if (CMODE == 0) {
        #pragma unroll
        for (int r = 0; r < 4; ++r) C[(size_t)(row0 + r) * N + col] = vr[r];
      } else if (CMODE == 1) {
        #pragma unroll
        for (int r = 0; r < 4; ++r) Cb[(size_t)(row0 + r) * N + col] = __float2bfloat16(vr[r]);
      } else {  // CMODE 4
        const int bb = row0 >> 10, t0v = row0 & 1023;   // row = b*T + t
        if (col < D_) {                                  // K head
          const int hh = col >> 7, dd = col & 127;
          #pragma unroll
          for (int r = 0; r < 4; ++r) {
            const size_t idx = (((size_t)(bb * H_ + hh)) * T_ + t0v + r) * DH_ + dd;
            C[idx] = vr[r];
            Cb[idx] = __float2bfloat16(vr[r]);
          }
        } else {                                         // V head (+ transposed bf16)
          const int c2 = col - D_;
          const int hh = c2 >> 7, dd = c2 & 127;
          #pragma unroll
          for (int r = 0; r < 4; ++r)
            C2[(((size_t)(bb * H_ + hh)) * T_ + t0v + r) * DH_ + dd] = vr[r];
          __hip_bfloat16 tmp[4];
          #pragma unroll
          for (int r = 0; r < 4; ++r) tmp[r] = __float2bfloat16(vr[r]);
          *(sh4*)(Cb2 + (((size_t)(bb * H_ + hh)) * DH_ + dd) * T_ + t0v) = *(const sh4*)tmp;
        }
      }
    }
  }
}

// ---------------------------------------------------------------------------
// prep_all: one launch for x-prep + 5 weight conversions.
// y==0 (x-blocks 0..255): read x once (float4), write xb (bf16, 8B store),
//   local EMA scan per 16-row chunk (fp32), and compact chunk-final lf.
// y==1..5: fp32->bf16 weight conversion (16B short8 stores).
// ---------------------------------------------------------------------------
__global__ __launch_bounds__(256)
void prep_all(const float* __restrict__ x, __hip_bfloat16* __restrict__ xb,
              float* __restrict__ l2, float* __restrict__ lf,
              const float* __restrict__ s1, const float* __restrict__ s2,
              const float* __restrict__ s3, const float* __restrict__ s4,
              const float* __restrict__ s5,
              __hip_bfloat16* d1, __hip_bfloat16* d2, __hip_bfloat16* d3,
              __hip_bfloat16* d4, __hip_bfloat16* d5,
              int n1, int n2, int n3, int n4, int n5)
{
  if (blockIdx.y == 0) {
    const int bid = blockIdx.x;
    if (bid >= 256) return;
    const int dblk = bid & 1;
    const int ch   = (bid >> 1) & 63;
    const int b    = bid >> 7;
    const int t0 = ch * CH_;
    const int d  = dblk * 1024 + threadIdx.x * 4;
    const float* xp = x  + (size_t)b * T_ * D_ + d;
    float*       lp = l2 + (size_t)b * T_ * D_ + d;
    __hip_bfloat16* xo = xb + (size_t)b * T_ * D_ + d;
    float4 s = make_float4(0.f, 0.f, 0.f, 0.f);
    #pragma unroll 4
    for (int t = t0; t < t0 + CH_; ++t) {
      float4 v = *(const float4*)(xp + (size_t)t * D_);
      __hip_bfloat16 tmp[4] = {__float2bfloat16(v.x), __float2bfloat16(v.y),
                               __float2bfloat16(v.z), __float2bfloat16(v.w)};
      *(sh4*)(xo + (size_t)t * D_) = *(const sh4*)tmp;
      s.x = 0.9f * s.x + 0.1f * v.x;
      s.y = 0.9f * s.y + 0.1f * v.y;
      s.z = 0.9f * s.z + 0.1f * v.z;
      s.w = 0.9f * s.w + 0.1f * v.w;
      *(float4*)(lp + (size_t)t * D_) = s;
    }
    // compact chunk-final for the carry computation in fuse_router
    *(float4*)(lf + ((size_t)b * NCH_ + ch) * D_ + d) = s;
    return;
  }
  const float* s; __hip_bfloat16* d; int n;
  switch (blockIdx.y) {
    case 1: s = s1; d = d1; n = n1; break;
    case 2: s = s2; d = d2; n = n2; break;
    case 3: s = s3; d = d3; n = n3; break;
    case 4: s = s4; d = d4; n = n4; break;
    default: s = s5; d = d5; n = n5; break;
  }
  const int i = (blockIdx.x * 256 + threadIdx.x) * 8;
  if (i < n) {
    float4 a = *(const float4*)(s + i);
    float4 b = *(const float4*)(s + i + 4);
    __hip_bfloat16 t[8] = {__float2bfloat16(a.x), __float2bfloat16(a.y),
                           __float2bfloat16(a.z), __float2bfloat16(a.w),
                           __float2bfloat16(b.x), __float2bfloat16(b.y),
                           __float2bfloat16(b.z), __float2bfloat16(b.w)};
    *(short8*)(d + i) = *(const short8*)t;
  }
}

// ---------------------------------------------------------------------------
// fuse_router: per block, 8 consecutive rows (all in ONE batch b and ONE
// EMA chunk ch since 8 | 16).
// Phase 1: lam = softmax(hdn @ rw2^T + rb2) per row (32-lane group dot).
// Phase 1b: carry(b,ch,:) computed inline as weighted sum over lf (L3-hot,
//   <=63 fma iterations/thread).
// Phase 2: fused = lam0*x + lam1*(l2 + 0.9^(off+1)*carry) + lam2*l3 -> bf16.
// ---------------------------------------------------------------------------
__global__ __launch_bounds__(256)
void fuse_router(const float* __restrict__ x, const float* __restrict__ l2,
                 const float* __restrict__ l3m, const float* __restrict__ hdn,
                 const float* __restrict__ rw2, const float* __restrict__ rb2,
                 const float* __restrict__ lf, float* __restrict__ lam,
                 __hip_bfloat16* __restrict__ fb)
{
  __shared__ float lamS[8][3];
  const int tid = threadIdx.x;
  const int g = tid >> 5, l32 = tid & 31;
  const int m = blockIdx.x * 8 + g;
  const float* hp = hdn + (size_t)m * DR_;
  float s0 = 0.f, s1 = 0.f, s2 = 0.f;
  #pragma unroll
  for (int it = 0; it < 8; ++it) {
    const int k = l32 * 4 + it * 128;
    float4 h4 = *(const float4*)(hp + k);
    float4 w0 = *(const float4*)(rw2 + k);
    float4 w1 = *(const float4*)(rw2 + DR_ + k);
    float4 w2 = *(const float4*)(rw2 + 2 * DR_ + k);
    s0 += h4.x * w0.x + h4.y * w0.y + h4.z * w0.z + h4.w * w0.w;
    s1 += h4.x * w1.x + h4.y * w1.y + h4.z * w1.z + h4.w * w1.w;
    s2 += h4.x * w2.x + h4.y * w2.y + h4.z * w2.z + h4.w * w2.w;
  }
  #pragma unroll
  for (int off = 16; off > 0; off >>= 1) {
    s0 += __shfl_xor(s0, off);
    s1 += __shfl_xor(s1, off);
    s2 += __shfl_xor(s2, off);
  }
  if (l32 == 0) {
    s0 += rb2[0]; s1 += rb2[1]; s2 += rb2[2];
    float mx = fmaxf(s0, fmaxf(s1, s2));
    float e0 = __expf(s0 - mx), e1 = __expf(s1 - mx), e2 = __expf(s2 - mx);
    float inv = 1.f / (e0 + e1 + e2);
    lam[(size_t)m * 3 + 0] = e0 * inv;
    lam[(size_t)m * 3 + 1] = e1 * inv;
    lam[(size_t)m * 3 + 2] = e2 * inv;
    lamS[g][0] = e0 * inv; lamS[g][1] = e1 * inv; lamS[g][2] = e2 * inv;
  }

  // inline carry for this block's single (b, ch):
  // carry = sum_{j<ch} (0.9^16)^(ch-1-j) * lf[b,j,:]
  const int m0b = blockIdx.x * 8;
  const int bb  = m0b >> 10;
  const int ch  = (m0b & 1023) >> 4;
  const int c   = tid * 8;
  float4 cv0 = make_float4(0.f, 0.f, 0.f, 0.f);
  float4 cv1 = make_float4(0.f, 0.f, 0.f, 0.f);
  {
    float w = 1.f;
    for (int j = ch - 1; j >= 0; --j) {
      const float* lp = lf + ((size_t)bb * NCH_ + j) * D_ + c;
      float4 a0 = *(const float4*)(lp);
      float4 a1 = *(const float4*)(lp + 4);
      cv0.x += w * a0.x; cv0.y += w * a0.y; cv0.z += w * a0.z; cv0.w += w * a0.w;
      cv1.x += w * a1.x; cv1.y += w * a1.y; cv1.z += w * a1.z; cv1.w += w * a1.w;
      w *= 0.18530201888518416f;              // 0.9^16
    }
  }
  __syncthreads();

  const int base = m0b & 15;                  // off base (0 or 8)
  #pragma unroll
  for (int r = 0; r < 8; ++r) {
    const int mm = m0b + r;
    const float pw = __expf((float)(base + r + 1) * -0.105360515657f);  // 0.9^(off+1)
    const float u0 = lamS[r][0], u1 = lamS[r][1], u2 = lamS[r][2];
    const float* xp = x   + (size_t)mm * D_ + c;
    const float* ep = l2  + (size_t)mm * D_ + c;
    const float* gp = l3m + (size_t)bb * D_ + c;
    __hip_bfloat16 tmp[8];
    {
      float4 xv = *(const float4*)(xp);
      float4 ev = *(const float4*)(ep);
      float4 gv = *(const float4*)(gp);
      tmp[0] = __float2bfloat16(u0 * xv.x + u1 * (ev.x + pw * cv0.x) + u2 * gv.x);
      tmp[1] = __float2bfloat16(u0 * xv.y + u1 * (ev.y + pw * cv0.y) + u2 * gv.y);
      tmp[2] = __float2bfloat16(u0 * xv.z + u1 * (ev.z + pw * cv0.z) + u2 * gv.z);
      tmp[3] = __float2bfloat16(u0 * xv.w + u1 * (ev.w + pw * cv0.w) + u2 * gv.w);
    }
    {
      float4 xv = *(const float4*)(xp + 4);
      float4 ev = *(const float4*)(ep + 4);
      float4 gv = *(const float4*)(gp + 4);
      tmp[4] = __float2bfloat16(u0 * xv.x + u1 * (ev.x + pw * cv1.x) + u2 * gv.x);
      tmp[5] = __float2bfloat16(u0 * xv.y + u1 * (ev.y + pw * cv1.y) + u2 * gv.y);
      tmp[6] = __float2bfloat16(u0 * xv.z + u1 * (ev.z + pw * cv1.z) + u2 * gv.z);
      tmp[7] = __float2bfloat16(u0 * xv.w + u1 * (ev.w + pw * cv1.w) + u2 * gv.w);
    }
    *(short8*)(fb + (size_t)mm * D_ + c) = *(const short8*)tmp;
  }
}

// ---------------------------------------------------------------------------
// MFMA flash attention. 64-row Q-tile per block, 4 waves x 16 q-rows,
// 64-key K-tiles, 16x16x32 bf16 MFMA for QK^T and PV.
// DOUBLE-BUFFERED K/V LDS, ONE barrier per iteration.  Ps is wave-private.
// LDS = 80,896 B -> 2 blocks/CU.  Grid: 1-D 512 with anti-correlated qt
// remap (co-resident pairs sum to 17 tile-iters).  Q fragments global->reg.
// Softmax: per-lane partial lrow (group-reduced ONCE at the end; alpha is
// group-uniform so partials scale identically) + T13 defer-max THR=8
// (wave-uniform via __all; skips alpha exps, lrow and oacc rescales).
// ---------------------------------------------------------------------------
__global__ __launch_bounds__(256)
void flash_mfma(const __hip_bfloat16* __restrict__ qg,
                const __hip_bfloat16* __restrict__ kg,
                const __hip_bfloat16* __restrict__ vg,
                __hip_bfloat16* __restrict__ og)
{
  __shared__ __hip_bfloat16 Ks[2][64 * 136];
  __shared__ __hip_bfloat16 Vt[2][128 * 72];
  __shared__ __hip_bfloat16 Ps[64 * 72];
  const int tid  = threadIdx.x;
  const int wave = tid >> 6, lane = tid & 63;
  const int L    = blockIdx.x;
  const int halfg = L >> 8, idx = L & 255;
  const int bh = (idx >> 4) | (halfg << 4);
  const int qt = halfg ? (15 - (idx & 15)) : (idx & 15);
  const int b = bh >> 4, h = bh & 15;
  const int q0 = qt * 64;
  const int lo = lane & 15, hi = lane >> 4;

  short8 aq[4];
  {
    const __hip_bfloat16* qsrc = qg + (size_t)(b * T_ + q0 + wave * 16 + lo) * D_ + h * DH_;
    #pragma unroll
    for (int kk = 0; kk < 4; ++kk)
      aq[kk] = *(const short8*)(qsrc + kk * 32 + hi * 8);
  }

  f32x4 oacc[8];
  #pragma unroll
  for (int i = 0; i < 8; ++i) oacc[i] = (f32x4)0.f;
  float mrow[4]  = {-INFINITY, -INFINITY, -INFINITY, -INFINITY};
  float lrowp[4] = {0.f, 0.f, 0.f, 0.f};        // per-lane partials

  const __hip_bfloat16* kbp = kg + (size_t)bh * T_ * DH_;
  const __hip_bfloat16* vbp = vg + (size_t)bh * DH_ * T_;
  const float scale = 0.08838834764831845f;      // 1/sqrt(128)

  short8 kreg[4], vreg[4];
  auto load_tile = [&](int k0) {
    #pragma unroll
    for (int i = 0; i < 4; ++i) {
      const int ci = tid + 256 * i;
      const int r = ci >> 4, j = ci & 15;
      kreg[i] = *(const short8*)(kbp + (size_t)(k0 + r) * DH_ + j * 8);
      const int dd = ci >> 3, j2 = ci & 7;
      vreg[i] = *(const short8*)(vbp + (size_t)dd * T_ + k0 + j2 * 8);
    }
  };
  auto write_lds = [&](int bf) {
    #pragma unroll
    for (int i = 0; i < 4; ++i) {
      const int ci = tid + 256 * i;
      const int r = ci >> 4, j = ci & 15;
      *(short8*)&Ks[bf][r * 136 + j * 8] = kreg[i];
      const int dd = ci >> 3, j2 = ci & 7;
      *(short8*)&Vt[bf][dd * 72 + j2 * 8] = vreg[i];
    }
  };

  load_tile(0);
  write_lds(0);                     // implicit vmcnt wait on tile-0 loads
  if (qt > 0) load_tile(64);        // tile 1 in flight across barrier
  __syncthreads();

  for (int kt = 0; kt <= qt; ++kt) {
    const int cur = kt & 1;
    f32x4 sc[4];
    __builtin_amdgcn_s_setprio(1);
    #pragma unroll
    for (int nt = 0; nt < 4; ++nt) {
      sc[nt] = (f32x4)0.f;
      #pragma unroll
      for (int kk = 0; kk < 4; ++kk) {
        short8 bk = *(const short8*)&Ks[cur][(nt * 16 + lo) * 136 + kk * 32 + hi * 8];
        sc[nt] = __builtin_amdgcn_mfma_f32_16x16x32_bf16(aq[kk], bk, sc[nt], 0, 0, 0);
      }
    }
    __builtin_amdgcn_s_setprio(0);
    #pragma unroll
    for (int nt = 0; nt < 4; ++nt)
      #pragma unroll
      for (int r = 0; r < 4; ++r) sc[nt][r] *= scale;
    if (kt == qt) {                           // mask only the diagonal tile
      const int qrow = q0 + wave * 16 + hi * 4;
      #pragma unroll
      for (int nt = 0; nt < 4; ++nt) {
        const int key = qt * 64 + nt * 16 + lo;
        #pragma unroll
        for (int r = 0; r < 4; ++r)
          if (key > qrow + r) sc[nt][r] = -1e30f;
      }
    }
    // group-reduced tile max per row
    float mxv[4];
    #pragma unroll
    for (int r = 0; r < 4; ++r) {
      float mx = fmaxf(fmaxf(sc[0][r], sc[1][r]), fmaxf(sc[2][r], sc[3][r]));
      mx = fmaxf(mx, __shfl_xor(mx, 1));
      mx = fmaxf(mx, __shfl_xor(mx, 2));
      mx = fmaxf(mx, __shfl_xor(mx, 4));
      mx = fmaxf(mx, __shfl_xor(mx, 8));
      mxv[r] = mx;
    }
    // T13 defer-max: skip rescale when all rows grew <= THR (wave-uniform)
    const bool deferLane = (mxv[0] <= mrow[0] + 8.f) & (mxv[1] <= mrow[1] + 8.f) &
                           (mxv[2] <= mrow[2] + 8.f) & (mxv[3] <= mrow[3] + 8.f);
    if (__all(deferLane)) {
      #pragma unroll
      for (int r = 0; r < 4; ++r) {
        float ls = 0.f;
        #pragma unroll
        for (int nt = 0; nt < 4; ++nt) {
          float p = __expf(sc[nt][r] - mrow[r]);
          sc[nt][r] = p;
          ls += p;
        }
        lrowp[r] += ls;                      // per-lane partial, no shuffle
      }
    } else {
      float alpha[4];
      #pragma unroll
      for (int r = 0; r < 4; ++r) {
        const float nm = fmaxf(mrow[r], mxv[r]);
        alpha[r] = __expf(mrow[r] - nm);
        mrow[r] = nm;
        float ls = 0.f;
        #pragma unroll
        for (int nt = 0; nt < 4; ++nt) {
          float p = __expf(sc[nt][r] - nm);
          sc[nt][r] = p;
          ls += p;
        }
        lrowp[r] = lrowp[r] * alpha[r] + ls;
      }
      #pragma unroll
      for (int n2 = 0; n2 < 8; ++n2)
        #pragma unroll
        for (int r = 0; r < 4; ++r) oacc[n2][r] *= alpha[r];
    }
    #pragma unroll
    for (int nt = 0; nt < 4; ++nt)
      #pragma unroll
      for (int r = 0; r < 4; ++r)
        Ps[(wave * 16 + hi * 4 + r) * 72 + nt * 16 + lo] = __float2bfloat16(sc[nt][r]);
    short8 ap[2];
    #pragma unroll
    for (int k2 = 0; k2 < 2; ++k2)
      ap[k2] = *(const short8*)&Ps[(wave * 16 + lo) * 72 + k2 * 32 + hi * 8];
    __builtin_amdgcn_s_setprio(1);
    #pragma unroll
    for (int n2 = 0; n2 < 8; ++n2) {
      #pragma unroll
      for (int k2 = 0; k2 < 2; ++k2) {
        short8 bv = *(const short8*)&Vt[cur][(n2 * 16 + lo) * 72 + k2 * 32 + hi * 8];
        oacc[n2] = __builtin_amdgcn_mfma_f32_16x16x32_bf16(ap[k2], bv, oacc[n2], 0, 0, 0);
      }
    }
    __builtin_amdgcn_s_setprio(0);
    if (kt < qt) {
      write_lds(cur ^ 1);           // vmcnt waits only on tile kt+1 loads
      if (kt + 1 < qt) load_tile((kt + 2) * 64);
    }
    __syncthreads();                // single barrier per iteration
  }

  // final cross-lane lrow reduction (once, not per tile)
  float inv[4];
  #pragma unroll
  for (int r = 0; r < 4; ++r) {
    float l = lrowp[r];
    l += __shfl_xor(l, 1);
    l += __shfl_xor(l, 2);
    l += __shfl_xor(l, 4);
    l += __shfl_xor(l, 8);
    inv[r] = 1.f / l;
  }
  __hip_bfloat16* od = og + (size_t)(b * T_ + q0 + wave * 16 + hi * 4) * D_ + h * DH_;
  #pragma unroll
  for (int n2 = 0; n2 < 8; ++n2)
    #pragma unroll
    for (int r = 0; r < 4; ++r)
      od[(size_t)r * D_ + n2 * 16 + lo] = __float2bfloat16(oacc[n2][r] * inv[r]);
}

// ---------------------------------------------------------------------------
extern "C" void kernel_launch(void* const* d_in, const int* in_sizes, int n_in,
                              void* d_out, int out_size, void* d_ws, size_t ws_size,
                              hipStream_t stream)
{
  const float* x   = (const float*)d_in[0];
  const float* l3m = (const float*)d_in[1];
  const float* wq  = (const float*)d_in[2];
  const float* wk  = (const float*)d_in[3];
  const float* wv  = (const float*)d_in[4];
  const float* wo  = (const float*)d_in[5];
  const float* rw1 = (const float*)d_in[6];
  const float* rb1 = (const float*)d_in[7];
  const float* rw2 = (const float*)d_in[8];
  const float* rb2 = (const float*)d_in[9];

  float* out = (float*)d_out;                 // [b,t,d]      4,194,304 f32
  float* kh  = out + 4194304;                 // [b,h,t,dh]   4,194,304 f32
  float* vh  = out + 8388608;                 // [b,h,t,dh]   4,194,304 f32
  float* lam = out + 12582912;                // [b,t,3]          6,144 f32

  // ws layout (80 MB):
  char* wsb = (char*)d_ws;
  float*          l2_f32 = (float*)(wsb);                        // 16 MB (local scan)
  float*          hdn    = (float*)(wsb + (16u << 20));          //  8 MB
  __hip_bfloat16* wkb    = (__hip_bfloat16*)(wsb + (24u << 20)); //  8 MB \ contiguous
  __hip_bfloat16* wvb    = (__hip_bfloat16*)(wsb + (32u << 20)); //  8 MB / [4096,2048]
  __hip_bfloat16* wob    = (__hip_bfloat16*)(wsb + (40u << 20)); //  8 MB
  __hip_bfloat16* fusedb = (__hip_bfloat16*)(wsb + (48u << 20)); //  8 MB
  __hip_bfloat16* attnb  = (__hip_bfloat16*)(wsb + (56u << 20)); //  8 MB (written step 6)
  __hip_bfloat16* khb    = (__hip_bfloat16*)(wsb + (64u << 20)); //  8 MB bf16 heads
  __hip_bfloat16* vtb    = (__hip_bfloat16*)(wsb + (72u << 20)); //  8 MB bf16 [b,h,dh,t]
  float*          lf     = (float*)(wsb + (57u << 20));   // 1 MB chunk-finals (in attnb region; dead before flash)
  // d_out scratch reuse (regions written later in the stream order):
  __hip_bfloat16* wqb  = (__hip_bfloat16*)kh;                    // [16,24 MB) of d_out
  __hip_bfloat16* rw1b = (__hip_bfloat16*)kh + 4194304;          // [24,28 MB)
  __hip_bfloat16* xb   = (__hip_bfloat16*)vh;                    // [32,40 MB)
  __hip_bfloat16* qb   = (__hip_bfloat16*)out;                   // [0,8 MB); out written last

  dim3 blk(256);

  // 1. prep (x -> xb + EMA local scan + lf) and weight cvts, one launch
  prep_all<<<dim3(2048, 6), blk, 0, stream>>>(x, xb, l2_f32, lf,
                                              wq, wk, wv, wo, rw1,
                                              wqb, wkb, wvb, wob, rw1b,
                                              D_ * D_, D_ * D_, D_ * D_, D_ * D_, DR_ * D_);
  // 2. qb = bf16(x @ wq^T)   (64x128 tiles -> 512 WGs)
  gemm_mfma<64, 1, false><<<dim3(16, 32), blk, 0, stream>>>(xb, wqb, nullptr, nullptr, qb, nullptr, nullptr, M_, D_, D_);
  // 3. hdn = silu(q @ rw1^T + rb1)   (64x128 -> 256 WGs)
  gemm_mfma<64, 0, true><<<dim3(8, 32), blk, 0, stream>>>(qb, rw1b, rb1, hdn, nullptr, nullptr, nullptr, M_, DR_, D_);
  // 4. router + inline EMA carry + fuse in one kernel (writes lam, fusedb)
  fuse_router<<<dim3(256), blk, 0, stream>>>(x, l2_f32, l3m, hdn, rw2, rb2, lf, lam, fusedb);
  // 5. merged KV GEMM (N=4096): kh fp32+khb bf16 heads; vh fp32+vtb bf16 transposed
  gemm_mfma<128, 4, false><<<dim3(32, 16), blk, 0, stream>>>(fusedb, wkb, nullptr, kh, khb, vh, vtb, M_, 2 * D_, D_);
  // 6. MFMA flash attention -> bf16 attnb [b,t,d]  (balanced 1-D grid)
  flash_mfma<<<dim3(512), blk, 0, stream>>>(qb, khb, vtb, attnb);
  // 7. out = attn @ wo^T   (64x128 -> 512 WGs)
  gemm_mfma<64, 0, false><<<dim3(16, 32), blk, 0, stream>>>(attnb, wob, nullptr, out, nullptr, nullptr, nullptr, M_, D_, D_);
}

// Round 9
// 320.995 us; speedup vs baseline: 1.1165x; 1.0629x over previous
//
#include <hip/hip_runtime.h>
#include <hip/hip_bf16.h>
#include <math.h>

#define B_  2
#define T_  1024
#define D_  2048
#define H_  16
#define DH_ 128
#define M_  2048          // B_*T_
#define DR_ 1024          // D_/2
#define CH_  16           // EMA chunk length
#define NCH_ 64           // chunks per sequence (T_/CH_)

typedef __attribute__((ext_vector_type(8))) short short8;
typedef __attribute__((ext_vector_type(4))) short sh4;
typedef __attribute__((ext_vector_type(4))) float f32x4;

// async global->LDS, 16B per lane, dest = wave-uniform base + lane*16
__device__ __forceinline__ void gld16(const __hip_bfloat16* g, __hip_bfloat16* l) {
  __builtin_amdgcn_global_load_lds(
      (const __attribute__((address_space(1))) unsigned int*)g,
      (__attribute__((address_space(3))) unsigned int*)l, 16, 0, 0);
}

// ---------------------------------------------------------------------------
// bf16 MFMA GEMM: C = act(A * B^T + bias). A:[M,K] bf16 rm, B:[N,K] bf16 rm.
// BM x 128 tile, BK=64 (two 32-col halves), double-buffered LDS, 2-phase
// pipeline: stage(t+1) issued BEFORE compute(t); one __syncthreads per
// K-step.  256 threads = 4 waves in 2x2.
// KNOWN-GOOD plateau config (~51us KV): BK=32 (r7), counted-vmcnt 4-buf
// (r3), and XCD swizzle (r6) all regressed — do not touch without the
// full 8-wave 256-square template (which can't win at M=2048: <=128 WGs).
// A/B staging shares ONE array AB so the epilogue can legally reuse the
// full 64KB as scratch (V-transpose tile).
// CMODE 0: C fp32 [M,N].   CMODE 1: Cb bf16 [M,N] only.
// CMODE 4: merged KV. col<2048: C fp32 heads + Cb bf16 heads (k).
//          col>=2048: C2 fp32 heads + Cb2 bf16 transposed [b,h,dh,t] (v)
//          via LDS-transpose epilogue -> full-line coalesced stores
//          (direct 8B stores at stride 2KB caused TCC RMW: +17MB fetch).
// ---------------------------------------------------------------------------
template<int BM, int CMODE, bool SILU>
__global__ __launch_bounds__(256)
void gemm_mfma(const __hip_bfloat16* __restrict__ A,
               const __hip_bfloat16* __restrict__ Bm,
               const float* __restrict__ bias,
               float* __restrict__ C, __hip_bfloat16* __restrict__ Cb,
               float* __restrict__ C2, __hip_bfloat16* __restrict__ Cb2,
               int M, int N, int K)
{
  constexpr int NI = BM / 32;           // A-fragment rows per wave (4 or 2)
  constexpr int AC = BM / 64;           // A gld16 calls per wave per half (2 or 1)
  constexpr int ROWS = BM + 128;        // A rows + B rows per (buf,half)
  __shared__ __hip_bfloat16 AB[2][2][ROWS * 32];   // As = [0,BM*32), Bs = [BM*32,..)
  const int tid  = threadIdx.x;
  const int wave = tid >> 6;
  const int lane = tid & 63;
  const int m0 = blockIdx.y * BM;
  const int n0 = blockIdx.x * 128;
  const int wm = (wave >> 1) * (BM / 2);   // wave's row half
  const int wn = (wave & 1) * 64;          // wave's col half

  const int srow = lane >> 2;              // 0..15 row within 16-row group
  const int scol = (lane & 3) * 8;         // bf16 element offset in k
  const __hip_bfloat16* Ag = A  + (size_t)(m0 + wave * (BM / 4) + srow) * K + scol;
  const __hip_bfloat16* Bg = Bm + (size_t)(n0 + wave * 32 + srow) * K + scol;

  const int fr = lane & 15;                // fragment row (m/n index)
  const int fk = (lane >> 4) * 8;          // fragment k offset

  f32x4 acc[NI][4];
  #pragma unroll
  for (int i = 0; i < NI; ++i)
    #pragma unroll
    for (int j = 0; j < 4; ++j) acc[i][j] = (f32x4)0.f;

  // stage one BK=64 tile (both 32-col halves) into buffer bf
  auto stage = [&](int bf, int k0) {
    #pragma unroll
    for (int h = 0; h < 2; ++h) {
      #pragma unroll
      for (int c = 0; c < AC; ++c)
        gld16(Ag + k0 + h * 32 + (size_t)(c * 16) * K,
              &AB[bf][h][(wave * (BM / 4) + c * 16) * 32]);
      #pragma unroll
      for (int c = 0; c < 2; ++c)
        gld16(Bg + k0 + h * 32 + (size_t)(c * 16) * K,
              &AB[bf][h][(BM + wave * 32 + c * 16) * 32]);
    }
  };

  stage(0, 0);
  __syncthreads();                         // prologue drain (vmcnt(0))
  int cur = 0;
  for (int k0 = 0; k0 < K; k0 += 64) {
    if (k0 + 64 < K) stage(cur ^ 1, k0 + 64);   // issue next tile FIRST
    #pragma unroll
    for (int h = 0; h < 2; ++h) {
      short8 af[NI], bfr[4];
      #pragma unroll
      for (int i = 0; i < NI; ++i)
        af[i]  = *(const short8*)&AB[cur][h][(wm + i * 16 + fr) * 32 + fk];
      #pragma unroll
      for (int j = 0; j < 4; ++j)
        bfr[j] = *(const short8*)&AB[cur][h][(BM + wn + j * 16 + fr) * 32 + fk];
      #pragma unroll
      for (int i = 0; i < NI; ++i)
        #pragma unroll
        for (int j = 0; j < 4; ++j)
          acc[i][j] = __builtin_amdgcn_mfma_f32_16x16x32_bf16(af[i], bfr[j], acc[i][j], 0, 0, 0);
    }
    __syncthreads();   // vmcnt(0)+lgkmcnt(0) drain: next tile landed, reads done
    cur ^= 1;
  }

  // ------------------------ V-block epilogue (CMODE 4, n0>=D_) -------------
  if constexpr (CMODE == 4) {
    if (n0 >= D_) {
      // block covers one head (hh), dd 0..127, t0v..t0v+127 (128-aligned)
      __hip_bfloat16* flat = &AB[0][0][0];           // 64KB scratch, all reads done
      const int bb  = m0 >> 10, t0v = m0 & 1023;
      const int hh  = (n0 - D_) >> 7;
      #pragma unroll
      for (int i = 0; i < NI; ++i) {
        const int tl0 = wm + i * 16 + (lane >> 4) * 4;   // local t (mult of 4)
        #pragma unroll
        for (int j = 0; j < 4; ++j) {
          const int ddl = wn + j * 16 + (lane & 15);     // local dd
          __hip_bfloat16 tmp[4];
          #pragma unroll
          for (int r = 0; r < 4; ++r) {
            const float v = acc[i][j][r];
            C2[(((size_t)(bb * H_ + hh)) * T_ + t0v + tl0 + r) * DH_ + ddl] = v;
            tmp[r] = __float2bfloat16(v);
          }
          *(sh4*)(flat + ddl * 136 + tl0) = *(const sh4*)tmp;  // stride-136 pad
        }
      }
      __syncthreads();
      const int dd = tid >> 1, th = (tid & 1) * 64;
      __hip_bfloat16* dst = Cb2 + (((size_t)(bb * H_ + hh)) * DH_ + dd) * T_ + t0v + th;
      const __hip_bfloat16* srcl = flat + dd * 136 + th;
      #pragma unroll
      for (int q = 0; q < 8; ++q)                       // full 64B lines along t
        *(short8*)(dst + q * 8) = *(const short8*)(srcl + q * 8);
      return;
    }
  }

  // C/D layout (m89-verified): col = lane&15, row = (lane>>4)*4 + reg
  #pragma unroll
  for (int i = 0; i < NI; ++i) {
    #pragma unroll
    for (int j = 0; j < 4; ++j) {
      const int row0 = m0 + wm + i * 16 + (lane >> 4) * 4;
      const int col  = n0 + wn + j * 16 + (lane & 15);
      float vr[4];
      #pragma unroll
      for (int r = 0; r < 4; ++r) {
        float v = acc[i][j][r];
        if (bias) v += bias[col];
        if (SILU) v = v / (1.f + __expf(-v));
        vr[r] = v;
      }
      if (CMODE == 0) {
        #pragma unroll
        for (int r = 0; r < 4; ++r) C[(size_t)(row0 + r) * N + col] = vr[r];
      } else if (CMODE == 1) {
        #pragma unroll
        for (int r = 0; r < 4; ++r) Cb[(size_t)(row0 + r) * N + col] = __float2bfloat16(vr[r]);
      } else {  // CMODE 4, K-head block
        const int bb = row0 >> 10, t0v = row0 & 1023;   // row = b*T + t
        const int hh = col >> 7, dd = col & 127;
        #pragma unroll
        for (int r = 0; r < 4; ++r) {
          const size_t idx = (((size_t)(bb * H_ + hh)) * T_ + t0v + r) * DH_ + dd;
          C[idx] = vr[r];
          Cb[idx] = __float2bfloat16(vr[r]);
        }
      }
    }
  }
}

// ---------------------------------------------------------------------------
// prep_all: one launch for x-prep + 5 weight conversions.
// y==0 (x-blocks 0..255): read x once (float4), write xb (bf16, 8B store),
//   local EMA scan per 16-row chunk (fp32), and compact chunk-final lf.
// y==1..5: fp32->bf16 weight conversion (16B short8 stores).
// ---------------------------------------------------------------------------
__global__ __launch_bounds__(256)
void prep_all(const float* __restrict__ x, __hip_bfloat16* __restrict__ xb,
              float* __restrict__ l2, float* __restrict__ lf,
              const float* __restrict__ s1, const float* __restrict__ s2,
              const float* __restrict__ s3, const float* __restrict__ s4,
              const float* __restrict__ s5,
              __hip_bfloat16* d1, __hip_bfloat16* d2, __hip_bfloat16* d3,
              __hip_bfloat16* d4, __hip_bfloat16* d5,
              int n1, int n2, int n3, int n4, int n5)
{
  if (blockIdx.y == 0) {
    const int bid = blockIdx.x;
    if (bid >= 256) return;
    const int dblk = bid & 1;
    const int ch   = (bid >> 1) & 63;
    const int b    = bid >> 7;
    const int t0 = ch * CH_;
    const int d  = dblk * 1024 + threadIdx.x * 4;
    const float* xp = x  + (size_t)b * T_ * D_ + d;
    float*       lp = l2 + (size_t)b * T_ * D_ + d;
    __hip_bfloat16* xo = xb + (size_t)b * T_ * D_ + d;
    float4 s = make_float4(0.f, 0.f, 0.f, 0.f);
    #pragma unroll 4
    for (int t = t0; t < t0 + CH_; ++t) {
      float4 v = *(const float4*)(xp + (size_t)t * D_);
      __hip_bfloat16 tmp[4] = {__float2bfloat16(v.x), __float2bfloat16(v.y),
                               __float2bfloat16(v.z), __float2bfloat16(v.w)};
      *(sh4*)(xo + (size_t)t * D_) = *(const sh4*)tmp;
      s.x = 0.9f * s.x + 0.1f * v.x;
      s.y = 0.9f * s.y + 0.1f * v.y;
      s.z = 0.9f * s.z + 0.1f * v.z;
      s.w = 0.9f * s.w + 0.1f * v.w;
      *(float4*)(lp + (size_t)t * D_) = s;
    }
    // compact chunk-final for the carry computation in fuse_router
    *(float4*)(lf + ((size_t)b * NCH_ + ch) * D_ + d) = s;
    return;
  }
  const float* s; __hip_bfloat16* d; int n;
  switch (blockIdx.y) {
    case 1: s = s1; d = d1; n = n1; break;
    case 2: s = s2; d = d2; n = n2; break;
    case 3: s = s3; d = d3; n = n3; break;
    case 4: s = s4; d = d4; n = n4; break;
    default: s = s5; d = d5; n = n5; break;
  }
  const int i = (blockIdx.x * 256 + threadIdx.x) * 8;
  if (i < n) {
    float4 a = *(const float4*)(s + i);
    float4 b = *(const float4*)(s + i + 4);
    __hip_bfloat16 t[8] = {__float2bfloat16(a.x), __float2bfloat16(a.y),
                           __float2bfloat16(a.z), __float2bfloat16(a.w),
                           __float2bfloat16(b.x), __float2bfloat16(b.y),
                           __float2bfloat16(b.z), __float2bfloat16(b.w)};
    *(short8*)(d + i) = *(const short8*)t;
  }
}

// ---------------------------------------------------------------------------
// fuse_router: per block, 8 consecutive rows (all in ONE batch b and ONE
// EMA chunk ch since 8 | 16).
// Phase 1: lam = softmax(hdn @ rw2^T + rb2) per row (32-lane group dot).
// Phase 1b: carry(b,ch,:) computed inline as weighted sum over lf (L3-hot,
//   <=63 fma iterations/thread).
// Phase 2: fused = lam0*x + lam1*(l2 + 0.9^(off+1)*carry) + lam2*l3 -> bf16.
// ---------------------------------------------------------------------------
__global__ __launch_bounds__(256)
void fuse_router(const float* __restrict__ x, const float* __restrict__ l2,
                 const float* __restrict__ l3m, const float* __restrict__ hdn,
                 const float* __restrict__ rw2, const float* __restrict__ rb2,
                 const float* __restrict__ lf, float* __restrict__ lam,
                 __hip_bfloat16* __restrict__ fb)
{
  __shared__ float lamS[8][3];
  const int tid = threadIdx.x;
  const int g = tid >> 5, l32 = tid & 31;
  const int m = blockIdx.x * 8 + g;
  const float* hp = hdn + (size_t)m * DR_;
  float s0 = 0.f, s1 = 0.f, s2 = 0.f;
  #pragma unroll
  for (int it = 0; it < 8; ++it) {
    const int k = l32 * 4 + it * 128;
    float4 h4 = *(const float4*)(hp + k);
    float4 w0 = *(const float4*)(rw2 + k);
    float4 w1 = *(const float4*)(rw2 + DR_ + k);
    float4 w2 = *(const float4*)(rw2 + 2 * DR_ + k);
    s0 += h4.x * w0.x + h4.y * w0.y + h4.z * w0.z + h4.w * w0.w;
    s1 += h4.x * w1.x + h4.y * w1.y + h4.z * w1.z + h4.w * w1.w;
    s2 += h4.x * w2.x + h4.y * w2.y + h4.z * w2.z + h4.w * w2.w;
  }
  #pragma unroll
  for (int off = 16; off > 0; off >>= 1) {
    s0 += __shfl_xor(s0, off);
    s1 += __shfl_xor(s1, off);
    s2 += __shfl_xor(s2, off);
  }
  if (l32 == 0) {
    s0 += rb2[0]; s1 += rb2[1]; s2 += rb2[2];
    float mx = fmaxf(s0, fmaxf(s1, s2));
    float e0 = __expf(s0 - mx), e1 = __expf(s1 - mx), e2 = __expf(s2 - mx);
    float inv = 1.f / (e0 + e1 + e2);
    lam[(size_t)m * 3 + 0] = e0 * inv;
    lam[(size_t)m * 3 + 1] = e1 * inv;
    lam[(size_t)m * 3 + 2] = e2 * inv;
    lamS[g][0] = e0 * inv; lamS[g][1] = e1 * inv; lamS[g][2] = e2 * inv;
  }

  // inline carry for this block's single (b, ch):
  // carry = sum_{j<ch} (0.9^16)^(ch-1-j) * lf[b,j,:]
  const int m0b = blockIdx.x * 8;
  const int bb  = m0b >> 10;
  const int ch  = (m0b & 1023) >> 4;
  const int c   = tid * 8;
  float4 cv0 = make_float4(0.f, 0.f, 0.f, 0.f);
  float4 cv1 = make_float4(0.f, 0.f, 0.f, 0.f);
  {
    float w = 1.f;
    for (int j = ch - 1; j >= 0; --j) {
      const float* lp = lf + ((size_t)bb * NCH_ + j) * D_ + c;
      float4 a0 = *(const float4*)(lp);
      float4 a1 = *(const float4*)(lp + 4);
      cv0.x += w * a0.x; cv0.y += w * a0.y; cv0.z += w * a0.z; cv0.w += w * a0.w;
      cv1.x += w * a1.x; cv1.y += w * a1.y; cv1.z += w * a1.z; cv1.w += w * a1.w;
      w *= 0.18530201888518416f;              // 0.9^16
    }
  }
  __syncthreads();

  const int base = m0b & 15;                  // off base (0 or 8)
  #pragma unroll
  for (int r = 0; r < 8; ++r) {
    const int mm = m0b + r;
    const float pw = __expf((float)(base + r + 1) * -0.105360515657f);  // 0.9^(off+1)
    const float u0 = lamS[r][0], u1 = lamS[r][1], u2 = lamS[r][2];
    const float* xp = x   + (size_t)mm * D_ + c;
    const float* ep = l2  + (size_t)mm * D_ + c;
    const float* gp = l3m + (size_t)bb * D_ + c;
    __hip_bfloat16 tmp[8];
    {
      float4 xv = *(const float4*)(xp);
      float4 ev = *(const float4*)(ep);
      float4 gv = *(const float4*)(gp);
      tmp[0] = __float2bfloat16(u0 * xv.x + u1 * (ev.x + pw * cv0.x) + u2 * gv.x);
      tmp[1] = __float2bfloat16(u0 * xv.y + u1 * (ev.y + pw * cv0.y) + u2 * gv.y);
      tmp[2] = __float2bfloat16(u0 * xv.z + u1 * (ev.z + pw * cv0.z) + u2 * gv.z);
      tmp[3] = __float2bfloat16(u0 * xv.w + u1 * (ev.w + pw * cv0.w) + u2 * gv.w);
    }
    {
      float4 xv = *(const float4*)(xp + 4);
      float4 ev = *(const float4*)(ep + 4);
      float4 gv = *(const float4*)(gp + 4);
      tmp[4] = __float2bfloat16(u0 * xv.x + u1 * (ev.x + pw * cv1.x) + u2 * gv.x);
      tmp[5] = __float2bfloat16(u0 * xv.y + u1 * (ev.y + pw * cv1.y) + u2 * gv.y);
      tmp[6] = __float2bfloat16(u0 * xv.z + u1 * (ev.z + pw * cv1.z) + u2 * gv.z);
      tmp[7] = __float2bfloat16(u0 * xv.w + u1 * (ev.w + pw * cv1.w) + u2 * gv.w);
    }
    *(short8*)(fb + (size_t)mm * D_ + c) = *(const short8*)tmp;
  }
}

// ---------------------------------------------------------------------------
// MFMA flash attention. 64-row Q-tile per block, 4 waves x 16 q-rows,
// 64-key K-tiles, 16x16x32 bf16 MFMA for QK^T and PV.
// DOUBLE-BUFFERED K/V LDS, ONE barrier per iteration.  Ps is wave-private.
// LDS = 80,896 B -> 2 blocks/CU.  Grid: 1-D 512 with anti-correlated qt
// remap (co-resident pairs sum to 17 tile-iters).  Q fragments global->reg.
// Softmax: per-lane partial lrow (group-reduced ONCE at the end) + T13
// defer-max THR=8 (wave-uniform via __all).
// ---------------------------------------------------------------------------
__global__ __launch_bounds__(256)
void flash_mfma(const __hip_bfloat16* __restrict__ qg,
                const __hip_bfloat16* __restrict__ kg,
                const __hip_bfloat16* __restrict__ vg,
                __hip_bfloat16* __restrict__ og)
{
  __shared__ __hip_bfloat16 Ks[2][64 * 136];
  __shared__ __hip_bfloat16 Vt[2][128 * 72];
  __shared__ __hip_bfloat16 Ps[64 * 72];
  const int tid  = threadIdx.x;
  const int wave = tid >> 6, lane = tid & 63;
  const int L    = blockIdx.x;
  const int halfg = L >> 8, idx = L & 255;
  const int bh = (idx >> 4) | (halfg << 4);
  const int qt = halfg ? (15 - (idx & 15)) : (idx & 15);
  const int b = bh >> 4, h = bh & 15;
  const int q0 = qt * 64;
  const int lo = lane & 15, hi = lane >> 4;

  short8 aq[4];
  {
    const __hip_bfloat16* qsrc = qg + (size_t)(b * T_ + q0 + wave * 16 + lo) * D_ + h * DH_;
    #pragma unroll
    for (int kk = 0; kk < 4; ++kk)
      aq[kk] = *(const short8*)(qsrc + kk * 32 + hi * 8);
  }

  f32x4 oacc[8];
  #pragma unroll
  for (int i = 0; i < 8; ++i) oacc[i] = (f32x4)0.f;
  float mrow[4]  = {-INFINITY, -INFINITY, -INFINITY, -INFINITY};
  float lrowp[4] = {0.f, 0.f, 0.f, 0.f};        // per-lane partials

  const __hip_bfloat16* kbp = kg + (size_t)bh * T_ * DH_;
  const __hip_bfloat16* vbp = vg + (size_t)bh * DH_ * T_;
  const float scale = 0.08838834764831845f;      // 1/sqrt(128)

  short8 kreg[4], vreg[4];
  auto load_tile = [&](int k0) {
    #pragma unroll
    for (int i = 0; i < 4; ++i) {
      const int ci = tid + 256 * i;
      const int r = ci >> 4, j = ci & 15;
      kreg[i] = *(const short8*)(kbp + (size_t)(k0 + r) * DH_ + j * 8);
      const int dd = ci >> 3, j2 = ci & 7;
      vreg[i] = *(const short8*)(vbp + (size_t)dd * T_ + k0 + j2 * 8);
    }
  };
  auto write_lds = [&](int bf) {
    #pragma unroll
    for (int i = 0; i < 4; ++i) {
      const int ci = tid + 256 * i;
      const int r = ci >> 4, j = ci & 15;
      *(short8*)&Ks[bf][r * 136 + j * 8] = kreg[i];
      const int dd = ci >> 3, j2 = ci & 7;
      *(short8*)&Vt[bf][dd * 72 + j2 * 8] = vreg[i];
    }
  };

  load_tile(0);
  write_lds(0);                     // implicit vmcnt wait on tile-0 loads
  if (qt > 0) load_tile(64);        // tile 1 in flight across barrier
  __syncthreads();

  for (int kt = 0; kt <= qt; ++kt) {
    const int cur = kt & 1;
    f32x4 sc[4];
    __builtin_amdgcn_s_setprio(1);
    #pragma unroll
    for (int nt = 0; nt < 4; ++nt) {
      sc[nt] = (f32x4)0.f;
      #pragma unroll
      for (int kk = 0; kk < 4; ++kk) {
        short8 bk = *(const short8*)&Ks[cur][(nt * 16 + lo) * 136 + kk * 32 + hi * 8];
        sc[nt] = __builtin_amdgcn_mfma_f32_16x16x32_bf16(aq[kk], bk, sc[nt], 0, 0, 0);
      }
    }
    __builtin_amdgcn_s_setprio(0);
    #pragma unroll
    for (int nt = 0; nt < 4; ++nt)
      #pragma unroll
      for (int r = 0; r < 4; ++r) sc[nt][r] *= scale;
    if (kt == qt) {                           // mask only the diagonal tile
      const int qrow = q0 + wave * 16 + hi * 4;
      #pragma unroll
      for (int nt = 0; nt < 4; ++nt) {
        const int key = qt * 64 + nt * 16 + lo;
        #pragma unroll
        for (int r = 0; r < 4; ++r)
          if (key > qrow + r) sc[nt][r] = -1e30f;
      }
    }
    // group-reduced tile max per row
    float mxv[4];
    #pragma unroll
    for (int r = 0; r < 4; ++r) {
      float mx = fmaxf(fmaxf(sc[0][r], sc[1][r]), fmaxf(sc[2][r], sc[3][r]));
      mx = fmaxf(mx, __shfl_xor(mx, 1));
      mx = fmaxf(mx, __shfl_xor(mx, 2));
      mx = fmaxf(mx, __shfl_xor(mx, 4));
      mx = fmaxf(mx, __shfl_xor(mx, 8));
      mxv[r] = mx;
    }
    // T13 defer-max: skip rescale when all rows grew <= THR (wave-uniform)
    const bool deferLane = (mxv[0] <= mrow[0] + 8.f) & (mxv[1] <= mrow[1] + 8.f) &
                           (mxv[2] <= mrow[2] + 8.f) & (mxv[3] <= mrow[3] + 8.f);
    if (__all(deferLane)) {
      #pragma unroll
      for (int r = 0; r < 4; ++r) {
        float ls = 0.f;
        #pragma unroll
        for (int nt = 0; nt < 4; ++nt) {
          float p = __expf(sc[nt][r] - mrow[r]);
          sc[nt][r] = p;
          ls += p;
        }
        lrowp[r] += ls;                      // per-lane partial, no shuffle
      }
    } else {
      float alpha[4];
      #pragma unroll
      for (int r = 0; r < 4; ++r) {
        const float nm = fmaxf(mrow[r], mxv[r]);
        alpha[r] = __expf(mrow[r] - nm);
        mrow[r] = nm;
        float ls = 0.f;
        #pragma unroll
        for (int nt = 0; nt < 4; ++nt) {
          float p = __expf(sc[nt][r] - nm);
          sc[nt][r] = p;
          ls += p;
        }
        lrowp[r] = lrowp[r] * alpha[r] + ls;
      }
      #pragma unroll
      for (int n2 = 0; n2 < 8; ++n2)
        #pragma unroll
        for (int r = 0; r < 4; ++r) oacc[n2][r] *= alpha[r];
    }
    #pragma unroll
    for (int nt = 0; nt < 4; ++nt)
      #pragma unroll
      for (int r = 0; r < 4; ++r)
        Ps[(wave * 16 + hi * 4 + r) * 72 + nt * 16 + lo] = __float2bfloat16(sc[nt][r]);
    short8 ap[2];
    #pragma unroll
    for (int k2 = 0; k2 < 2; ++k2)
      ap[k2] = *(const short8*)&Ps[(wave * 16 + lo) * 72 + k2 * 32 + hi * 8];
    __builtin_amdgcn_s_setprio(1);
    #pragma unroll
    for (int n2 = 0; n2 < 8; ++n2) {
      #pragma unroll
      for (int k2 = 0; k2 < 2; ++k2) {
        short8 bv = *(const short8*)&Vt[cur][(n2 * 16 + lo) * 72 + k2 * 32 + hi * 8];
        oacc[n2] = __builtin_amdgcn_mfma_f32_16x16x32_bf16(ap[k2], bv, oacc[n2], 0, 0, 0);
      }
    }
    __builtin_amdgcn_s_setprio(0);
    if (kt < qt) {
      write_lds(cur ^ 1);           // vmcnt waits only on tile kt+1 loads
      if (kt + 1 < qt) load_tile((kt + 2) * 64);
    }
    __syncthreads();                // single barrier per iteration
  }

  // final cross-lane lrow reduction (once, not per tile)
  float inv[4];
  #pragma unroll
  for (int r = 0; r < 4; ++r) {
    float l = lrowp[r];
    l += __shfl_xor(l, 1);
    l += __shfl_xor(l, 2);
    l += __shfl_xor(l, 4);
    l += __shfl_xor(l, 8);
    inv[r] = 1.f / l;
  }
  __hip_bfloat16* od = og + (size_t)(b * T_ + q0 + wave * 16 + hi * 4) * D_ + h * DH_;
  #pragma unroll
  for (int n2 = 0; n2 < 8; ++n2)
    #pragma unroll
    for (int r = 0; r < 4; ++r)
      od[(size_t)r * D_ + n2 * 16 + lo] = __float2bfloat16(oacc[n2][r] * inv[r]);
}

// ---------------------------------------------------------------------------
extern "C" void kernel_launch(void* const* d_in, const int* in_sizes, int n_in,
                              void* d_out, int out_size, void* d_ws, size_t ws_size,
                              hipStream_t stream)
{
  const float* x   = (const float*)d_in[0];
  const float* l3m = (const float*)d_in[1];
  const float* wq  = (const float*)d_in[2];
  const float* wk  = (const float*)d_in[3];
  const float* wv  = (const float*)d_in[4];
  const float* wo  = (const float*)d_in[5];
  const float* rw1 = (const float*)d_in[6];
  const float* rb1 = (const float*)d_in[7];
  const float* rw2 = (const float*)d_in[8];
  const float* rb2 = (const float*)d_in[9];

  float* out = (float*)d_out;                 // [b,t,d]      4,194,304 f32
  float* kh  = out + 4194304;                 // [b,h,t,dh]   4,194,304 f32
  float* vh  = out + 8388608;                 // [b,h,t,dh]   4,194,304 f32
  float* lam = out + 12582912;                // [b,t,3]          6,144 f32

  // ws layout (80 MB):
  char* wsb = (char*)d_ws;
  float*          l2_f32 = (float*)(wsb);                        // 16 MB (local scan)
  float*          hdn    = (float*)(wsb + (16u << 20));          //  8 MB
  __hip_bfloat16* wkb    = (__hip_bfloat16*)(wsb + (24u << 20)); //  8 MB \ contiguous
  __hip_bfloat16* wvb    = (__hip_bfloat16*)(wsb + (32u << 20)); //  8 MB / [4096,2048]
  __hip_bfloat16* wob    = (__hip_bfloat16*)(wsb + (40u << 20)); //  8 MB
  __hip_bfloat16* fusedb = (__hip_bfloat16*)(wsb + (48u << 20)); //  8 MB
  __hip_bfloat16* attnb  = (__hip_bfloat16*)(wsb + (56u << 20)); //  8 MB (written step 6)
  __hip_bfloat16* khb    = (__hip_bfloat16*)(wsb + (64u << 20)); //  8 MB bf16 heads
  __hip_bfloat16* vtb    = (__hip_bfloat16*)(wsb + (72u << 20)); //  8 MB bf16 [b,h,dh,t]
  float*          lf     = (float*)(wsb + (57u << 20));   // 1 MB chunk-finals (in attnb region; dead before flash)
  // d_out scratch reuse (regions written later in the stream order):
  __hip_bfloat16* wqb  = (__hip_bfloat16*)kh;                    // [16,24 MB) of d_out
  __hip_bfloat16* rw1b = (__hip_bfloat16*)kh + 4194304;          // [24,28 MB)
  __hip_bfloat16* xb   = (__hip_bfloat16*)vh;                    // [32,40 MB)
  __hip_bfloat16* qb   = (__hip_bfloat16*)out;                   // [0,8 MB); out written last

  dim3 blk(256);

  // 1. prep (x -> xb + EMA local scan + lf) and weight cvts, one launch
  prep_all<<<dim3(2048, 6), blk, 0, stream>>>(x, xb, l2_f32, lf,
                                              wq, wk, wv, wo, rw1,
                                              wqb, wkb, wvb, wob, rw1b,
                                              D_ * D_, D_ * D_, D_ * D_, D_ * D_, DR_ * D_);
  // 2. qb = bf16(x @ wq^T)   (64x128 tiles -> 512 WGs)
  gemm_mfma<64, 1, false><<<dim3(16, 32), blk, 0, stream>>>(xb, wqb, nullptr, nullptr, qb, nullptr, nullptr, M_, D_, D_);
  // 3. hdn = silu(q @ rw1^T + rb1)   (64x128 -> 256 WGs)
  gemm_mfma<64, 0, true><<<dim3(8, 32), blk, 0, stream>>>(qb, rw1b, rb1, hdn, nullptr, nullptr, nullptr, M_, DR_, D_);
  // 4. router + inline EMA carry + fuse in one kernel (writes lam, fusedb)
  fuse_router<<<dim3(256), blk, 0, stream>>>(x, l2_f32, l3m, hdn, rw2, rb2, lf, lam, fusedb);
  // 5. merged KV GEMM (N=4096): kh fp32+khb bf16 heads; vh fp32+vtb bf16 transposed
  gemm_mfma<128, 4, false><<<dim3(32, 16), blk, 0, stream>>>(fusedb, wkb, nullptr, kh, khb, vh, vtb, M_, 2 * D_, D_);
  // 6. MFMA flash attention -> bf16 attnb [b,t,d]  (balanced 1-D grid)
  flash_mfma<<<dim3(512), blk, 0, stream>>>(qb, khb, vtb, attnb);
  // 7. out = attn @ wo^T   (64x128 -> 512 WGs)
  gemm_mfma<64, 0, false><<<dim3(16, 32), blk, 0, stream>>>(attnb, wob, nullptr, out, nullptr, nullptr, nullptr, M_, D_, D_);
}

// Round 10
// 308.164 us; speedup vs baseline: 1.1629x; 1.0416x over previous
//
#include <hip/hip_runtime.h>
#include <hip/hip_bf16.h>
#include <math.h>

#define B_  2
#define T_  1024
#define D_  2048
#define H_  16
#define DH_ 128
#define M_  2048          // B_*T_
#define DR_ 1024          // D_/2
#define CH_  16           // EMA chunk length
#define NCH_ 64           // chunks per sequence (T_/CH_)

typedef __attribute__((ext_vector_type(8))) short short8;
typedef __attribute__((ext_vector_type(4))) short sh4;
typedef __attribute__((ext_vector_type(4))) float f32x4;

// async global->LDS, 16B per lane, dest = wave-uniform base + lane*16
__device__ __forceinline__ void gld16(const __hip_bfloat16* g, __hip_bfloat16* l) {
  __builtin_amdgcn_global_load_lds(
      (const __attribute__((address_space(1))) unsigned int*)g,
      (__attribute__((address_space(3))) unsigned int*)l, 16, 0, 0);
}

// ---------------------------------------------------------------------------
// bf16 MFMA GEMM: C = act(A * B^T + bias). A:[M,K] bf16 rm, B:[N,K] bf16 rm.
// BM x 128 tile, BK=64 (two 32-col halves), double-buffered LDS, 2-phase
// pipeline: stage(t+1) issued BEFORE compute(t); one __syncthreads per
// K-step.  256 threads = 4 waves in 2x2.
// KNOWN-GOOD plateau config (~47us KV): BK=32 (r7), counted-vmcnt 4-buf
// (r3), and XCD swizzle (r6) all regressed — do not touch without the
// full 8-wave 256-square template (which can't win at M=2048: <=128 WGs).
// CVTW: blockIdx.z==1 blocks are weight-conversion workers (fp32->bf16,
// 3 matrices) riding the launch's spare CU slots — the hdn GEMM has only
// 256 WGs at 49KB LDS, so conversions run truly concurrent (free).
// CMODE 0: C fp32 [M,N].   CMODE 1: Cb bf16 [M,N] only.
// CMODE 4: merged KV. col<2048: C fp32 heads + Cb bf16 heads (k).
//          col>=2048: C2 fp32 heads + Cb2 bf16 transposed [b,h,dh,t] (v)
//          via LDS-transpose epilogue (r9: removed TCC RMW, WRITE 58->49MB).
// ---------------------------------------------------------------------------
template<int BM, int CMODE, bool SILU, bool CVTW>
__global__ __launch_bounds__(256)
void gemm_mfma(const __hip_bfloat16* __restrict__ A,
               const __hip_bfloat16* __restrict__ Bm,
               const float* __restrict__ bias,
               float* __restrict__ C, __hip_bfloat16* __restrict__ Cb,
               float* __restrict__ C2, __hip_bfloat16* __restrict__ Cb2,
               const float* __restrict__ cw0, const float* __restrict__ cw1,
               const float* __restrict__ cw2,
               __hip_bfloat16* __restrict__ dw0, __hip_bfloat16* __restrict__ dw1,
               __hip_bfloat16* __restrict__ dw2,
               int M, int N, int K)
{
  if constexpr (CVTW) {
    if (blockIdx.z == 1) {            // conversion worker blocks
      const int bid = blockIdx.y * gridDim.x + blockIdx.x;   // 0..255
      const float* s_[3] = {cw0, cw1, cw2};
      __hip_bfloat16* d_[3] = {dw0, dw1, dw2};
      #pragma unroll
      for (int w = 0; w < 3; ++w) {
        for (int chunk = bid; chunk < 2048; chunk += 256) {
          const int i = chunk * 2048 + threadIdx.x * 8;      // D_*D_ = 2048*2048
          float4 a = *(const float4*)(s_[w] + i);
          float4 b = *(const float4*)(s_[w] + i + 4);
          __hip_bfloat16 t[8] = {__float2bfloat16(a.x), __float2bfloat16(a.y),
                                 __float2bfloat16(a.z), __float2bfloat16(a.w),
                                 __float2bfloat16(b.x), __float2bfloat16(b.y),
                                 __float2bfloat16(b.z), __float2bfloat16(b.w)};
          *(short8*)(d_[w] + i) = *(const short8*)t;
        }
      }
      return;
    }
  }

  constexpr int NI = BM / 32;           // A-fragment rows per wave (4 or 2)
  constexpr int AC = BM / 64;           // A gld16 calls per wave per half (2 or 1)
  constexpr int ROWS = BM + 128;        // A rows + B rows per (buf,half)
  __shared__ __hip_bfloat16 AB[2][2][ROWS * 32];   // As = [0,BM*32), Bs = [BM*32,..)
  const int tid  = threadIdx.x;
  const int wave = tid >> 6;
  const int lane = tid & 63;
  const int m0 = blockIdx.y * BM;
  const int n0 = blockIdx.x * 128;
  const int wm = (wave >> 1) * (BM / 2);   // wave's row half
  const int wn = (wave & 1) * 64;          // wave's col half

  const int srow = lane >> 2;              // 0..15 row within 16-row group
  const int scol = (lane & 3) * 8;         // bf16 element offset in k
  const __hip_bfloat16* Ag = A  + (size_t)(m0 + wave * (BM / 4) + srow) * K + scol;
  const __hip_bfloat16* Bg = Bm + (size_t)(n0 + wave * 32 + srow) * K + scol;

  const int fr = lane & 15;                // fragment row (m/n index)
  const int fk = (lane >> 4) * 8;          // fragment k offset

  f32x4 acc[NI][4];
  #pragma unroll
  for (int i = 0; i < NI; ++i)
    #pragma unroll
    for (int j = 0; j < 4; ++j) acc[i][j] = (f32x4)0.f;

  // stage one BK=64 tile (both 32-col halves) into buffer bf
  auto stage = [&](int bf, int k0) {
    #pragma unroll
    for (int h = 0; h < 2; ++h) {
      #pragma unroll
      for (int c = 0; c < AC; ++c)
        gld16(Ag + k0 + h * 32 + (size_t)(c * 16) * K,
              &AB[bf][h][(wave * (BM / 4) + c * 16) * 32]);
      #pragma unroll
      for (int c = 0; c < 2; ++c)
        gld16(Bg + k0 + h * 32 + (size_t)(c * 16) * K,
              &AB[bf][h][(BM + wave * 32 + c * 16) * 32]);
    }
  };

  stage(0, 0);
  __syncthreads();                         // prologue drain (vmcnt(0))
  int cur = 0;
  for (int k0 = 0; k0 < K; k0 += 64) {
    if (k0 + 64 < K) stage(cur ^ 1, k0 + 64);   // issue next tile FIRST
    #pragma unroll
    for (int h = 0; h < 2; ++h) {
      short8 af[NI], bfr[4];
      #pragma unroll
      for (int i = 0; i < NI; ++i)
        af[i]  = *(const short8*)&AB[cur][h][(wm + i * 16 + fr) * 32 + fk];
      #pragma unroll
      for (int j = 0; j < 4; ++j)
        bfr[j] = *(const short8*)&AB[cur][h][(BM + wn + j * 16 + fr) * 32 + fk];
      #pragma unroll
      for (int i = 0; i < NI; ++i)
        #pragma unroll
        for (int j = 0; j < 4; ++j)
          acc[i][j] = __builtin_amdgcn_mfma_f32_16x16x32_bf16(af[i], bfr[j], acc[i][j], 0, 0, 0);
    }
    __syncthreads();   // vmcnt(0)+lgkmcnt(0) drain: next tile landed, reads done
    cur ^= 1;
  }

  // ------------------------ V-block epilogue (CMODE 4, n0>=D_) -------------
  if constexpr (CMODE == 4) {
    if (n0 >= D_) {
      // block covers one head (hh), dd 0..127, t0v..t0v+127 (128-aligned)
      __hip_bfloat16* flat = &AB[0][0][0];           // 64KB scratch, all reads done
      const int bb  = m0 >> 10, t0v = m0 & 1023;
      const int hh  = (n0 - D_) >> 7;
      #pragma unroll
      for (int i = 0; i < NI; ++i) {
        const int tl0 = wm + i * 16 + (lane >> 4) * 4;   // local t (mult of 4)
        #pragma unroll
        for (int j = 0; j < 4; ++j) {
          const int ddl = wn + j * 16 + (lane & 15);     // local dd
          __hip_bfloat16 tmp[4];
          #pragma unroll
          for (int r = 0; r < 4; ++r) {
            const float v = acc[i][j][r];
            C2[(((size_t)(bb * H_ + hh)) * T_ + t0v + tl0 + r) * DH_ + ddl] = v;
            tmp[r] = __float2bfloat16(v);
          }
          *(sh4*)(flat + ddl * 136 + tl0) = *(const sh4*)tmp;  // stride-136 pad
        }
      }
      __syncthreads();
      const int dd = tid >> 1, th = (tid & 1) * 64;
      __hip_bfloat16* dst = Cb2 + (((size_t)(bb * H_ + hh)) * DH_ + dd) * T_ + t0v + th;
      const __hip_bfloat16* srcl = flat + dd * 136 + th;
      #pragma unroll
      for (int q = 0; q < 8; ++q)                       // full 64B lines along t
        *(short8*)(dst + q * 8) = *(const short8*)(srcl + q * 8);
      return;
    }
  }

  // C/D layout (m89-verified): col = lane&15, row = (lane>>4)*4 + reg
  #pragma unroll
  for (int i = 0; i < NI; ++i) {
    #pragma unroll
    for (int j = 0; j < 4; ++j) {
      const int row0 = m0 + wm + i * 16 + (lane >> 4) * 4;
      const int col  = n0 + wn + j * 16 + (lane & 15);
      float vr[4];
      #pragma unroll
      for (int r = 0; r < 4; ++r) {
        float v = acc[i][j][r];
        if (bias) v += bias[col];
        if (SILU) v = v / (1.f + __expf(-v));
        vr[r] = v;
      }
      if (CMODE == 0) {
        #pragma unroll
        for (int r = 0; r < 4; ++r) C[(size_t)(row0 + r) * N + col] = vr[r];
      } else if (CMODE == 1) {
        #pragma unroll
        for (int r = 0; r < 4; ++r) Cb[(size_t)(row0 + r) * N + col] = __float2bfloat16(vr[r]);
      } else {  // CMODE 4, K-head block
        const int bb = row0 >> 10, t0v = row0 & 1023;   // row = b*T + t
        const int hh = col >> 7, dd = col & 127;
        #pragma unroll
        for (int r = 0; r < 4; ++r) {
          const size_t idx = (((size_t)(bb * H_ + hh)) * T_ + t0v + r) * DH_ + dd;
          C[idx] = vr[r];
          Cb[idx] = __float2bfloat16(vr[r]);
        }
      }
    }
  }
}

// ---------------------------------------------------------------------------
// prep_all: one launch for x-prep + 2 weight conversions (wq, rw1 — the
// ones needed by steps 2-3; wk/wv/wo ride the hdn-GEMM launch as CVTW).
// y==0 (x-blocks 0..255): read x once (float4), write xb (bf16, 8B store)
//   and the compact chunk-final lf (NO per-row l2 store: fuse_router
//   recomputes the local scan bitwise-identically from x).
// y==1: wq cvt; y==2: rw1 cvt (16B short8 stores).
// ---------------------------------------------------------------------------
__global__ __launch_bounds__(256)
void prep_all(const float* __restrict__ x, __hip_bfloat16* __restrict__ xb,
              float* __restrict__ lf,
              const float* __restrict__ s1, const float* __restrict__ s2,
              __hip_bfloat16* d1, __hip_bfloat16* d2,
              int n1, int n2)
{
  if (blockIdx.y == 0) {
    const int bid = blockIdx.x;
    if (bid >= 256) return;
    const int dblk = bid & 1;
    const int ch   = (bid >> 1) & 63;
    const int b    = bid >> 7;
    const int t0 = ch * CH_;
    const int d  = dblk * 1024 + threadIdx.x * 4;
    const float* xp = x  + (size_t)b * T_ * D_ + d;
    __hip_bfloat16* xo = xb + (size_t)b * T_ * D_ + d;
    float4 s = make_float4(0.f, 0.f, 0.f, 0.f);
    #pragma unroll 4
    for (int t = t0; t < t0 + CH_; ++t) {
      float4 v = *(const float4*)(xp + (size_t)t * D_);
      __hip_bfloat16 tmp[4] = {__float2bfloat16(v.x), __float2bfloat16(v.y),
                               __float2bfloat16(v.z), __float2bfloat16(v.w)};
      *(sh4*)(xo + (size_t)t * D_) = *(const sh4*)tmp;
      s.x = 0.9f * s.x + 0.1f * v.x;
      s.y = 0.9f * s.y + 0.1f * v.y;
      s.z = 0.9f * s.z + 0.1f * v.z;
      s.w = 0.9f * s.w + 0.1f * v.w;
    }
    // compact chunk-final for the carry computation in fuse_router
    *(float4*)(lf + ((size_t)b * NCH_ + ch) * D_ + d) = s;
    return;
  }
  const float* s; __hip_bfloat16* d; int n;
  if (blockIdx.y == 1) { s = s1; d = d1; n = n1; }
  else                 { s = s2; d = d2; n = n2; }
  const int i = (blockIdx.x * 256 + threadIdx.x) * 8;
  if (i < n) {
    float4 a = *(const float4*)(s + i);
    float4 b = *(const float4*)(s + i + 4);
    __hip_bfloat16 t[8] = {__float2bfloat16(a.x), __float2bfloat16(a.y),
                           __float2bfloat16(a.z), __float2bfloat16(a.w),
                           __float2bfloat16(b.x), __float2bfloat16(b.y),
                           __float2bfloat16(b.z), __float2bfloat16(b.w)};
    *(short8*)(d + i) = *(const short8*)t;
  }
}

// ---------------------------------------------------------------------------
// fuse_router: per block, 8 consecutive rows (all in ONE batch b and ONE
// EMA chunk ch since 8 | 16).
// Phase 1: lam = softmax(hdn @ rw2^T + rb2) per row (32-lane group dot).
// Phase 1b: carry(b,ch,:) computed inline as weighted sum over lf (L3-hot).
// Phase 2: local EMA scan recomputed inline from x (bitwise-identical
//   recurrence s=0.9s+0.1x from chunk start; reuses the x rows the fuse
//   loads anyway — replaces the 16MB l2 buffer), then
//   fused = lam0*x + lam1*(scan + 0.9^(off+1)*carry) + lam2*l3 -> bf16.
// ---------------------------------------------------------------------------
__global__ __launch_bounds__(256)
void fuse_router(const float* __restrict__ x,
                 const float* __restrict__ l3m, const float* __restrict__ hdn,
                 const float* __restrict__ rw2, const float* __restrict__ rb2,
                 const float* __restrict__ lf, float* __restrict__ lam,
                 __hip_bfloat16* __restrict__ fb)
{
  __shared__ float lamS[8][3];
  const int tid = threadIdx.x;
  const int g = tid >> 5, l32 = tid & 31;
  const int m = blockIdx.x * 8 + g;
  const float* hp = hdn + (size_t)m * DR_;
  float s0 = 0.f, s1 = 0.f, s2 = 0.f;
  #pragma unroll
  for (int it = 0; it < 8; ++it) {
    const int k = l32 * 4 + it * 128;
    float4 h4 = *(const float4*)(hp + k);
    float4 w0 = *(const float4*)(rw2 + k);
    float4 w1 = *(const float4*)(rw2 + DR_ + k);
    float4 w2 = *(const float4*)(rw2 + 2 * DR_ + k);
    s0 += h4.x * w0.x + h4.y * w0.y + h4.z * w0.z + h4.w * w0.w;
    s1 += h4.x * w1.x + h4.y * w1.y + h4.z * w1.z + h4.w * w1.w;
    s2 += h4.x * w2.x + h4.y * w2.y + h4.z * w2.z + h4.w * w2.w;
  }
  #pragma unroll
  for (int off = 16; off > 0; off >>= 1) {
    s0 += __shfl_xor(s0, off);
    s1 += __shfl_xor(s1, off);
    s2 += __shfl_xor(s2, off);
  }
  if (l32 == 0) {
    s0 += rb2[0]; s1 += rb2[1]; s2 += rb2[2];
    float mx = fmaxf(s0, fmaxf(s1, s2));
    float e0 = __expf(s0 - mx), e1 = __expf(s1 - mx), e2 = __expf(s2 - mx);
    float inv = 1.f / (e0 + e1 + e2);
    lam[(size_t)m * 3 + 0] = e0 * inv;
    lam[(size_t)m * 3 + 1] = e1 * inv;
    lam[(size_t)m * 3 + 2] = e2 * inv;
    lamS[g][0] = e0 * inv; lamS[g][1] = e1 * inv; lamS[g][2] = e2 * inv;
  }

  // inline carry for this block's single (b, ch):
  // carry = sum_{j<ch} (0.9^16)^(ch-1-j) * lf[b,j,:]
  const int m0b = blockIdx.x * 8;
  const int bb  = m0b >> 10;
  const int ch  = (m0b & 1023) >> 4;
  const int base = m0b & 15;                  // chunk offset base (0 or 8)
  const int c   = tid * 8;
  float4 cv0 = make_float4(0.f, 0.f, 0.f, 0.f);
  float4 cv1 = make_float4(0.f, 0.f, 0.f, 0.f);
  {
    float w = 1.f;
    for (int j = ch - 1; j >= 0; --j) {
      const float* lp = lf + ((size_t)bb * NCH_ + j) * D_ + c;
      float4 a0 = *(const float4*)(lp);
      float4 a1 = *(const float4*)(lp + 4);
      cv0.x += w * a0.x; cv0.y += w * a0.y; cv0.z += w * a0.z; cv0.w += w * a0.w;
      cv1.x += w * a1.x; cv1.y += w * a1.y; cv1.z += w * a1.z; cv1.w += w * a1.w;
      w *= 0.18530201888518416f;              // 0.9^16
    }
  }
  __syncthreads();

  // local EMA scan from chunk start (rows m0b-base .. m0b-1), identical
  // recurrence to prep's scan -> bitwise-identical values
  float4 e0v = make_float4(0.f, 0.f, 0.f, 0.f);
  float4 e1v = make_float4(0.f, 0.f, 0.f, 0.f);
  const float* xbase = x + (size_t)(m0b - base) * D_ + c;
  for (int j = 0; j < base; ++j) {            // 0 or 8 iterations
    float4 a0 = *(const float4*)(xbase + (size_t)j * D_);
    float4 a1 = *(const float4*)(xbase + (size_t)j * D_ + 4);
    e0v.x = 0.9f * e0v.x + 0.1f * a0.x; e0v.y = 0.9f * e0v.y + 0.1f * a0.y;
    e0v.z = 0.9f * e0v.z + 0.1f * a0.z; e0v.w = 0.9f * e0v.w + 0.1f * a0.w;
    e1v.x = 0.9f * e1v.x + 0.1f * a1.x; e1v.y = 0.9f * e1v.y + 0.1f * a1.y;
    e1v.z = 0.9f * e1v.z + 0.1f * a1.z; e1v.w = 0.9f * e1v.w + 0.1f * a1.w;
  }

  const float* gp = l3m + (size_t)bb * D_ + c;
  const float4 gv0 = *(const float4*)(gp);
  const float4 gv1 = *(const float4*)(gp + 4);
  #pragma unroll
  for (int r = 0; r < 8; ++r) {
    const int mm = m0b + r;
    const float pw = __expf((float)(base + r + 1) * -0.105360515657f);  // 0.9^(off+1)
    const float u0 = lamS[r][0], u1 = lamS[r][1], u2 = lamS[r][2];
    const float* xp = x + (size_t)mm * D_ + c;
    __hip_bfloat16 tmp[8];
    {
      float4 xv = *(const float4*)(xp);
      e0v.x = 0.9f * e0v.x + 0.1f * xv.x; e0v.y = 0.9f * e0v.y + 0.1f * xv.y;
      e0v.z = 0.9f * e0v.z + 0.1f * xv.z; e0v.w = 0.9f * e0v.w + 0.1f * xv.w;
      tmp[0] = __float2bfloat16(u0 * xv.x + u1 * (e0v.x + pw * cv0.x) + u2 * gv0.x);
      tmp[1] = __float2bfloat16(u0 * xv.y + u1 * (e0v.y + pw * cv0.y) + u2 * gv0.y);
      tmp[2] = __float2bfloat16(u0 * xv.z + u1 * (e0v.z + pw * cv0.z) + u2 * gv0.z);
      tmp[3] = __float2bfloat16(u0 * xv.w + u1 * (e0v.w + pw * cv0.w) + u2 * gv0.w);
    }
    {
      float4 xv = *(const float4*)(xp + 4);
      e1v.x = 0.9f * e1v.x + 0.1f * xv.x; e1v.y = 0.9f * e1v.y + 0.1f * xv.y;
      e1v.z = 0.9f * e1v.z + 0.1f * xv.z; e1v.w = 0.9f * e1v.w + 0.1f * xv.w;
      tmp[4] = __float2bfloat16(u0 * xv.x + u1 * (e1v.x + pw * cv1.x) + u2 * gv1.x);
      tmp[5] = __float2bfloat16(u0 * xv.y + u1 * (e1v.y + pw * cv1.y) + u2 * gv1.y);
      tmp[6] = __float2bfloat16(u0 * xv.z + u1 * (e1v.z + pw * cv1.z) + u2 * gv1.z);
      tmp[7] = __float2bfloat16(u0 * xv.w + u1 * (e1v.w + pw * cv1.w) + u2 * gv1.w);
    }
    *(short8*)(fb + (size_t)mm * D_ + c) = *(const short8*)tmp;
  }
}

// ---------------------------------------------------------------------------
// MFMA flash attention. 64-row Q-tile per block, 4 waves x 16 q-rows,
// 64-key K-tiles, 16x16x32 bf16 MFMA for QK^T and PV.
// DOUBLE-BUFFERED K/V LDS, ONE barrier per iteration.  Ps is wave-private.
// LDS = 80,896 B -> 2 blocks/CU.  Grid: 1-D 512 with anti-correlated qt
// remap (co-resident pairs sum to 17 tile-iters).  Q fragments global->reg.
// Softmax: per-lane partial lrow (group-reduced ONCE at the end) + T13
// defer-max THR=8 (wave-uniform via __all).
// ---------------------------------------------------------------------------
__global__ __launch_bounds__(256)
void flash_mfma(const __hip_bfloat16* __restrict__ qg,
                const __hip_bfloat16* __restrict__ kg,
                const __hip_bfloat16* __restrict__ vg,
                __hip_bfloat16* __restrict__ og)
{
  __shared__ __hip_bfloat16 Ks[2][64 * 136];
  __shared__ __hip_bfloat16 Vt[2][128 * 72];
  __shared__ __hip_bfloat16 Ps[64 * 72];
  const int tid  = threadIdx.x;
  const int wave = tid >> 6, lane = tid & 63;
  const int L    = blockIdx.x;
  const int halfg = L >> 8, idx = L & 255;
  const int bh = (idx >> 4) | (halfg << 4);
  const int qt = halfg ? (15 - (idx & 15)) : (idx & 15);
  const int b = bh >> 4, h = bh & 15;
  const int q0 = qt * 64;
  const int lo = lane & 15, hi = lane >> 4;

  short8 aq[4];
  {
    const __hip_bfloat16* qsrc = qg + (size_t)(b * T_ + q0 + wave * 16 + lo) * D_ + h * DH_;
    #pragma unroll
    for (int kk = 0; kk < 4; ++kk)
      aq[kk] = *(const short8*)(qsrc + kk * 32 + hi * 8);
  }

  f32x4 oacc[8];
  #pragma unroll
  for (int i = 0; i < 8; ++i) oacc[i] = (f32x4)0.f;
  float mrow[4]  = {-INFINITY, -INFINITY, -INFINITY, -INFINITY};
  float lrowp[4] = {0.f, 0.f, 0.f, 0.f};        // per-lane partials

  const __hip_bfloat16* kbp = kg + (size_t)bh * T_ * DH_;
  const __hip_bfloat16* vbp = vg + (size_t)bh * DH_ * T_;
  const float scale = 0.08838834764831845f;      // 1/sqrt(128)

  short8 kreg[4], vreg[4];
  auto load_tile = [&](int k0) {
    #pragma unroll
    for (int i = 0; i < 4; ++i) {
      const int ci = tid + 256 * i;
      const int r = ci >> 4, j = ci & 15;
      kreg[i] = *(const short8*)(kbp + (size_t)(k0 + r) * DH_ + j * 8);
      const int dd = ci >> 3, j2 = ci & 7;
      vreg[i] = *(const short8*)(vbp + (size_t)dd * T_ + k0 + j2 * 8);
    }
  };
  auto write_lds = [&](int bf) {
    #pragma unroll
    for (int i = 0; i < 4; ++i) {
      const int ci = tid + 256 * i;
      const int r = ci >> 4, j = ci & 15;
      *(short8*)&Ks[bf][r * 136 + j * 8] = kreg[i];
      const int dd = ci >> 3, j2 = ci & 7;
      *(short8*)&Vt[bf][dd * 72 + j2 * 8] = vreg[i];
    }
  };

  load_tile(0);
  write_lds(0);                     // implicit vmcnt wait on tile-0 loads
  if (qt > 0) load_tile(64);        // tile 1 in flight across barrier
  __syncthreads();

  for (int kt = 0; kt <= qt; ++kt) {
    const int cur = kt & 1;
    f32x4 sc[4];
    __builtin_amdgcn_s_setprio(1);
    #pragma unroll
    for (int nt = 0; nt < 4; ++nt) {
      sc[nt] = (f32x4)0.f;
      #pragma unroll
      for (int kk = 0; kk < 4; ++kk) {
        short8 bk = *(const short8*)&Ks[cur][(nt * 16 + lo) * 136 + kk * 32 + hi * 8];
        sc[nt] = __builtin_amdgcn_mfma_f32_16x16x32_bf16(aq[kk], bk, sc[nt], 0, 0, 0);
      }
    }
    __builtin_amdgcn_s_setprio(0);
    #pragma unroll
    for (int nt = 0; nt < 4; ++nt)
      #pragma unroll
      for (int r = 0; r < 4; ++r) sc[nt][r] *= scale;
    if (kt == qt) {                           // mask only the diagonal tile
      const int qrow = q0 + wave * 16 + hi * 4;
      #pragma unroll
      for (int nt = 0; nt < 4; ++nt) {
        const int key = qt * 64 + nt * 16 + lo;
        #pragma unroll
        for (int r = 0; r < 4; ++r)
          if (key > qrow + r) sc[nt][r] = -1e30f;
      }
    }
    // group-reduced tile max per row
    float mxv[4];
    #pragma unroll
    for (int r = 0; r < 4; ++r) {
      float mx = fmaxf(fmaxf(sc[0][r], sc[1][r]), fmaxf(sc[2][r], sc[3][r]));
      mx = fmaxf(mx, __shfl_xor(mx, 1));
      mx = fmaxf(mx, __shfl_xor(mx, 2));
      mx = fmaxf(mx, __shfl_xor(mx, 4));
      mx = fmaxf(mx, __shfl_xor(mx, 8));
      mxv[r] = mx;
    }
    // T13 defer-max: skip rescale when all rows grew <= THR (wave-uniform)
    const bool deferLane = (mxv[0] <= mrow[0] + 8.f) & (mxv[1] <= mrow[1] + 8.f) &
                           (mxv[2] <= mrow[2] + 8.f) & (mxv[3] <= mrow[3] + 8.f);
    if (__all(deferLane)) {
      #pragma unroll
      for (int r = 0; r < 4; ++r) {
        float ls = 0.f;
        #pragma unroll
        for (int nt = 0; nt < 4; ++nt) {
          float p = __expf(sc[nt][r] - mrow[r]);
          sc[nt][r] = p;
          ls += p;
        }
        lrowp[r] += ls;                      // per-lane partial, no shuffle
      }
    } else {
      float alpha[4];
      #pragma unroll
      for (int r = 0; r < 4; ++r) {
        const float nm = fmaxf(mrow[r], mxv[r]);
        alpha[r] = __expf(mrow[r] - nm);
        mrow[r] = nm;
        float ls = 0.f;
        #pragma unroll
        for (int nt = 0; nt < 4; ++nt) {
          float p = __expf(sc[nt][r] - nm);
          sc[nt][r] = p;
          ls += p;
        }
        lrowp[r] = lrowp[r] * alpha[r] + ls;
      }
      #pragma unroll
      for (int n2 = 0; n2 < 8; ++n2)
        #pragma unroll
        for (int r = 0; r < 4; ++r) oacc[n2][r] *= alpha[r];
    }
    #pragma unroll
    for (int nt = 0; nt < 4; ++nt)
      #pragma unroll
      for (int r = 0; r < 4; ++r)
        Ps[(wave * 16 + hi * 4 + r) * 72 + nt * 16 + lo] = __float2bfloat16(sc[nt][r]);
    short8 ap[2];
    #pragma unroll
    for (int k2 = 0; k2 < 2; ++k2)
      ap[k2] = *(const short8*)&Ps[(wave * 16 + lo) * 72 + k2 * 32 + hi * 8];
    __builtin_amdgcn_s_setprio(1);
    #pragma unroll
    for (int n2 = 0; n2 < 8; ++n2) {
      #pragma unroll
      for (int k2 = 0; k2 < 2; ++k2) {
        short8 bv = *(const short8*)&Vt[cur][(n2 * 16 + lo) * 72 + k2 * 32 + hi * 8];
        oacc[n2] = __builtin_amdgcn_mfma_f32_16x16x32_bf16(ap[k2], bv, oacc[n2], 0, 0, 0);
      }
    }
    __builtin_amdgcn_s_setprio(0);
    if (kt < qt) {
      write_lds(cur ^ 1);           // vmcnt waits only on tile kt+1 loads
      if (kt + 1 < qt) load_tile((kt + 2) * 64);
    }
    __syncthreads();                // single barrier per iteration
  }

  // final cross-lane lrow reduction (once, not per tile)
  float inv[4];
  #pragma unroll
  for (int r = 0; r < 4; ++r) {
    float l = lrowp[r];
    l += __shfl_xor(l, 1);
    l += __shfl_xor(l, 2);
    l += __shfl_xor(l, 4);
    l += __shfl_xor(l, 8);
    inv[r] = 1.f / l;
  }
  __hip_bfloat16* od = og + (size_t)(b * T_ + q0 + wave * 16 + hi * 4) * D_ + h * DH_;
  #pragma unroll
  for (int n2 = 0; n2 < 8; ++n2)
    #pragma unroll
    for (int r = 0; r < 4; ++r)
      od[(size_t)r * D_ + n2 * 16 + lo] = __float2bfloat16(oacc[n2][r] * inv[r]);
}

// ---------------------------------------------------------------------------
extern "C" void kernel_launch(void* const* d_in, const int* in_sizes, int n_in,
                              void* d_out, int out_size, void* d_ws, size_t ws_size,
                              hipStream_t stream)
{
  const float* x   = (const float*)d_in[0];
  const float* l3m = (const float*)d_in[1];
  const float* wq  = (const float*)d_in[2];
  const float* wk  = (const float*)d_in[3];
  const float* wv  = (const float*)d_in[4];
  const float* wo  = (const float*)d_in[5];
  const float* rw1 = (const float*)d_in[6];
  const float* rb1 = (const float*)d_in[7];
  const float* rw2 = (const float*)d_in[8];
  const float* rb2 = (const float*)d_in[9];

  float* out = (float*)d_out;                 // [b,t,d]      4,194,304 f32
  float* kh  = out + 4194304;                 // [b,h,t,dh]   4,194,304 f32
  float* vh  = out + 8388608;                 // [b,h,t,dh]   4,194,304 f32
  float* lam = out + 12582912;                // [b,t,3]          6,144 f32

  // ws layout (80 MB):
  char* wsb = (char*)d_ws;
  float*          hdn    = (float*)(wsb + (16u << 20));          //  8 MB
  __hip_bfloat16* wkb    = (__hip_bfloat16*)(wsb + (24u << 20)); //  8 MB \ contiguous
  __hip_bfloat16* wvb    = (__hip_bfloat16*)(wsb + (32u << 20)); //  8 MB / [4096,2048]
  __hip_bfloat16* wob    = (__hip_bfloat16*)(wsb + (40u << 20)); //  8 MB
  __hip_bfloat16* fusedb = (__hip_bfloat16*)(wsb + (48u << 20)); //  8 MB
  __hip_bfloat16* attnb  = (__hip_bfloat16*)(wsb + (56u << 20)); //  8 MB (written step 6)
  __hip_bfloat16* khb    = (__hip_bfloat16*)(wsb + (64u << 20)); //  8 MB bf16 heads
  __hip_bfloat16* vtb    = (__hip_bfloat16*)(wsb + (72u << 20)); //  8 MB bf16 [b,h,dh,t]
  float*          lf     = (float*)(wsb);                 // 1 MB chunk-finals
  // d_out scratch reuse (regions written later in the stream order):
  __hip_bfloat16* wqb  = (__hip_bfloat16*)kh;                    // [16,24 MB) of d_out
  __hip_bfloat16* rw1b = (__hip_bfloat16*)kh + 4194304;          // [24,28 MB)
  __hip_bfloat16* xb   = (__hip_bfloat16*)vh;                    // [32,40 MB)
  __hip_bfloat16* qb   = (__hip_bfloat16*)out;                   // [0,8 MB); out written last

  dim3 blk(256);

  // 1. prep: x -> xb + lf, and wq/rw1 cvts (rw1b needed by step 3 itself)
  prep_all<<<dim3(2048, 3), blk, 0, stream>>>(x, xb, lf, wq, rw1, wqb, rw1b,
                                              D_ * D_, DR_ * D_);
  // 2. qb = bf16(x @ wq^T)   (64x128 tiles -> 512 WGs)
  gemm_mfma<64, 1, false, false><<<dim3(16, 32), blk, 0, stream>>>(
      xb, wqb, nullptr, nullptr, qb, nullptr, nullptr,
      nullptr, nullptr, nullptr, nullptr, nullptr, nullptr, M_, D_, D_);
  // 3. hdn = silu(q @ rw1^T + rb1)  (256 GEMM WGs, z=1: wk/wv/wo cvt riding
  //    the spare CU slots — truly concurrent with the compute-bound GEMM)
  gemm_mfma<64, 0, true, true><<<dim3(8, 32, 2), blk, 0, stream>>>(
      qb, rw1b, rb1, hdn, nullptr, nullptr, nullptr,
      wk, wv, wo, wkb, wvb, wob, M_, DR_, D_);
  // 4. router + inline EMA carry + inline local scan + fuse (writes lam, fusedb)
  fuse_router<<<dim3(256), blk, 0, stream>>>(x, l3m, hdn, rw2, rb2, lf, lam, fusedb);
  // 5. merged KV GEMM (N=4096): kh fp32+khb bf16 heads; vh fp32+vtb bf16 transposed
  gemm_mfma<128, 4, false, false><<<dim3(32, 16), blk, 0, stream>>>(
      fusedb, wkb, nullptr, kh, khb, vh, vtb,
      nullptr, nullptr, nullptr, nullptr, nullptr, nullptr, M_, 2 * D_, D_);
  // 6. MFMA flash attention -> bf16 attnb [b,t,d]  (balanced 1-D grid)
  flash_mfma<<<dim3(512), blk, 0, stream>>>(qb, khb, vtb, attnb);
  // 7. out = attn @ wo^T   (64x128 -> 512 WGs)
  gemm_mfma<64, 0, false, false><<<dim3(16, 32), blk, 0, stream>>>(
      attnb, wob, nullptr, out, nullptr, nullptr, nullptr,
      nullptr, nullptr, nullptr, nullptr, nullptr, nullptr, M_, D_, D_);
}